// Round 10
// baseline (325.369 us; speedup 1.0000x reference)
//
#include <hip/hip_runtime.h>

// Problem constants
#define BDIM   8
#define NPIX   250000   // 500*500
#define G1N    62500    // 250*250
#define G2N    15625    // 125*125
#define NB0    977      // ceil(NPIX/256)
#define NB1    245      // ceil(G1N/256)
#define NB2    62       // ceil(G2N/256)
#define CAP0   4096
#define CAP1   4096
#define CAPM   2048
#define CH     64
#define ACH    128
#define NHEADS 4
#define DH     32
#define KSPLIT 4

static constexpr float BN_INV = 0.99999500003749969f;   // 1/sqrt(1+1e-5)
// attention scale folded into Q in exp2 domain: (1/sqrt(32)) * log2(e)
static constexpr float SCALE2 = 0.25505654734044769f;

typedef _Float16 f16x8 __attribute__((ext_vector_type(8)));
typedef float f32x4 __attribute__((ext_vector_type(4)));

// Workspace word offsets (4-byte units). Zeroed prefix: [0, E_ZEND)
static constexpr size_t E_MAP0  = 0;                                  // int [B*NPIX]
static constexpr size_t E_MAP1  = E_MAP0 + (size_t)BDIM*NPIX;         // int [B*G1N]
static constexpr size_t E_CNT   = E_MAP1 + (size_t)BDIM*G1N;          // int [32]
static constexpr size_t E_ZEND  = E_CNT + 32;
static constexpr size_t E_BC    = E_ZEND;                             // int [3][B][1024]
static constexpr size_t E_BO    = E_BC + (size_t)3*BDIM*1024;         // int [3][B][1024]
static constexpr size_t E_BM    = E_BO + (size_t)3*BDIM*1024;        // ull [3][B][1024][4]
static constexpr size_t E_LIST0 = E_BM + (size_t)3*BDIM*1024*8;      // int [B*CAP0]
static constexpr size_t E_LIST1 = E_LIST0 + (size_t)BDIM*CAP0;
static constexpr size_t E_LIST2 = E_LIST1 + (size_t)BDIM*CAP1;
static constexpr size_t E_Y0    = E_LIST2 + (size_t)BDIM*CAPM;        // f32 [B*CAP0*32]
static constexpr size_t E_Y1    = E_Y0 + (size_t)BDIM*CAP0*32;       // f32 [B*CAP1*64]
static constexpr size_t E_FE    = E_Y1 + (size_t)BDIM*CAP1*64;       // f32 [B*CAPM*64]
static constexpr size_t E_QF    = E_FE + (size_t)BDIM*CAPM*64;       // f16 [32bh][CAPM][32]
static constexpr size_t E_KF    = E_QF + (size_t)32*CAPM*32/2;
static constexpr size_t E_VT    = E_KF + (size_t)32*CAPM*32/2;       // f16 [32bh][32][CAPM]
static constexpr size_t E_O     = E_VT + (size_t)32*CAPM*32/2;       // f16 [B][CAPM][ACH]

// ---------------- deterministic compaction: count / scan / emit --------------

__device__ __forceinline__ bool act0(const float* x, int pix, int b) {
  return (pix < NPIX) && (x[(size_t)b * NPIX + pix] != 0.f);
}
__device__ __forceinline__ bool act1(const int* map0, int p, int b) {
  if (p >= G1N) return false;
  int i = p / 250, j = p - i * 250;
  const int* m = map0 + (size_t)b * NPIX + (2 * i) * 500 + 2 * j;
  return (m[0] | m[1] | m[500] | m[501]) != 0;
}
__device__ __forceinline__ bool act2(const int* map1, int p, int b) {
  if (p >= G2N) return false;
  int i = p / 125, j = p - i * 125;
  const int* m = map1 + (size_t)b * G1N + (2 * i) * 250 + 2 * j;
  return (m[0] | m[1] | m[250] | m[251]) != 0;
}

#define COUNT_BODY(ACT_EXPR)                                            \
  int idx = blockIdx.x * 256 + threadIdx.x;                             \
  int b = blockIdx.y;                                                   \
  bool act = (ACT_EXPR);                                                \
  unsigned long long mask = __ballot(act);                              \
  __shared__ int wc[4];                                                 \
  if ((threadIdx.x & 63) == 0) {                                        \
    wc[threadIdx.x >> 6] = __popcll(mask);                              \
    bm[((size_t)b * 1024 + blockIdx.x) * 4 + (threadIdx.x >> 6)] = mask;\
  }                                                                     \
  __syncthreads();                                                      \
  if (threadIdx.x == 0)                                                 \
    bcnt[b * 1024 + blockIdx.x] = wc[0] + wc[1] + wc[2] + wc[3];

__global__ void k_cnt0(const float* __restrict__ x, int* __restrict__ bcnt,
                       unsigned long long* __restrict__ bm) {
  COUNT_BODY(act0(x, idx, b))
}
__global__ void k_cnt1(const int* __restrict__ map0, int* __restrict__ bcnt,
                       unsigned long long* __restrict__ bm) {
  COUNT_BODY(act1(map0, idx, b))
}
__global__ void k_cnt2(const int* __restrict__ map1, int* __restrict__ bcnt,
                       unsigned long long* __restrict__ bm) {
  COUNT_BODY(act2(map1, idx, b))
}

// one block/image, 256 threads, shfl scan (1 barrier). nblk <= 1024.
__global__ __launch_bounds__(256) void k_scan(const int* __restrict__ bcnt,
                                              int* __restrict__ boff,
                                              int* __restrict__ cnt,
                                              int nblk, int cbase) {
  int b = blockIdx.x;
  int t = threadIdx.x;
  int base = t * 4;
  int v[4];
  int ts = 0;
#pragma unroll
  for (int u = 0; u < 4; ++u) {
    v[u] = (base + u < nblk) ? bcnt[b * 1024 + base + u] : 0;
    ts += v[u];
  }
  int lane = t & 63, w = t >> 6;
  int incl = ts;
#pragma unroll
  for (int off = 1; off < 64; off <<= 1) {
    int o = __shfl_up(incl, off, 64);
    if (lane >= off) incl += o;
  }
  __shared__ int wsum[4];
  if (lane == 63) wsum[w] = incl;
  __syncthreads();
  int woff = 0;
#pragma unroll
  for (int k = 0; k < 3; ++k) if (k < w) woff += wsum[k];
  int run = woff + incl - ts;
#pragma unroll
  for (int u = 0; u < 4; ++u) {
    if (base + u < nblk) boff[b * 1024 + base + u] = run;
    run += v[u];
  }
  if (t == 255) cnt[cbase + b] = run;
}

// emit: replay stored ballot masks (no recompute / no re-read of inputs)
#define EMIT_PROLOG                                                     \
  int idx = blockIdx.x * 256 + threadIdx.x;                             \
  int b = blockIdx.y;                                                   \
  int lane = threadIdx.x & 63;                                          \
  unsigned long long mask =                                             \
      bm[((size_t)b * 1024 + blockIdx.x) * 4 + (threadIdx.x >> 6)];     \
  bool act = (mask >> lane) & 1;                                        \
  __shared__ int wbase[4];                                              \
  if (lane == 0) wbase[threadIdx.x >> 6] = __popcll(mask);              \
  __syncthreads();                                                      \
  if (threadIdx.x == 0) {                                               \
    int s = boff[b * 1024 + blockIdx.x];                                \
    for (int w = 0; w < 4; ++w) { int c = wbase[w]; wbase[w] = s; s += c; } \
  }                                                                     \
  __syncthreads();                                                      \
  int slot = wbase[threadIdx.x >> 6] + __popcll(mask & ((1ull << lane) - 1ull));

__global__ void k_emit0(const unsigned long long* __restrict__ bm,
                        const int* __restrict__ boff,
                        int* __restrict__ map0, int* __restrict__ list0) {
  EMIT_PROLOG
  if (act && slot < CAP0) {
    list0[b * CAP0 + slot] = idx;
    map0[(size_t)b * NPIX + idx] = slot + 1;
  }
}
__global__ void k_emit1(const unsigned long long* __restrict__ bm,
                        const int* __restrict__ boff,
                        int* __restrict__ map1, int* __restrict__ list1) {
  EMIT_PROLOG
  if (act && slot < CAP1) {
    list1[b * CAP1 + slot] = idx;
    map1[(size_t)b * G1N + idx] = slot + 1;
  }
}
__global__ void k_emit2(const unsigned long long* __restrict__ bm,
                        const int* __restrict__ boff,
                        int* __restrict__ list2) {
  EMIT_PROLOG
  if (act && slot < CAPM) list2[b * CAPM + slot] = idx;
}

// ---------------- sparse convs -----------------------------------------------

__global__ void k_y0(const float* __restrict__ x, const float* __restrict__ w0,
                     const float* __restrict__ b0, const float* __restrict__ g0,
                     const float* __restrict__ be0,
                     const int* __restrict__ list0, const int* __restrict__ cnt,
                     float* __restrict__ y0) {
  int t = blockIdx.x * 256 + threadIdx.x;
  int b = t >> 17;
  int r = t & 131071;
  int slot = r >> 5, c = r & 31;
  int n = min(cnt[b], CAP0);
  if (slot >= n) return;
  int pix = list0[b * CAP0 + slot];
  int i = pix / 500, j = pix - i * 500;
  float acc = b0[c];
#pragma unroll
  for (int di = 0; di < 3; ++di) {
    int ii = i + di - 1;
    if ((unsigned)ii >= 500u) continue;
#pragma unroll
    for (int dj = 0; dj < 3; ++dj) {
      int jj = j + dj - 1;
      if ((unsigned)jj >= 500u) continue;
      acc += x[(size_t)b * NPIX + ii * 500 + jj] * w0[(di * 3 + dj) * 32 + c];
    }
  }
  float o = g0[c] * acc * BN_INV + be0[c];
  y0[((size_t)(b * CAP0) + slot) * 32 + c] = fmaxf(o, 0.f);
}

// 256 threads = 4 sub-blocks x 8 sites (32 sites/block)
__global__ __launch_bounds__(256) void k_y1(
    const float* __restrict__ y0, const float* __restrict__ w1,
    const float* __restrict__ b1, const float* __restrict__ g1,
    const float* __restrict__ be1,
    const int* __restrict__ map0, const int* __restrict__ list1,
    const int* __restrict__ cnt, float* __restrict__ y1) {
  int b = blockIdx.x & 7;
  int qblk = blockIdx.x >> 3;       // 0..127
  int sub = threadIdx.x >> 6;
  int co = threadIdx.x & 63;
  int n = min(cnt[BDIM + b], CAP1);
  if (qblk * 32 >= n) return;       // block-uniform
  int s0 = qblk * 32 + sub * 8;
  __shared__ float inT[4][4][32][8];
  for (int idx = co; idx < 1024; idx += 64) {
    int s = idx & 7;
    int r = idx >> 3;
    int ci = r & 31, pp = r >> 5;
    float v = 0.f;
    int sg = s0 + s;
    if (sg < n) {
      int p = list1[b * CAP1 + sg];
      int i = p / 250, j = p - i * 250;
      int sm = map0[(size_t)b * NPIX + (2 * i + (pp >> 1)) * 500 + (2 * j + (pp & 1))];
      if (sm) v = y0[((size_t)(b * CAP0) + (sm - 1)) * 32 + ci];
    }
    inT[sub][pp][ci][s] = v;
  }
  __syncthreads();
  float acc[8];
#pragma unroll
  for (int s = 0; s < 8; ++s) acc[s] = b1[co];
#pragma unroll 2
  for (int pp = 0; pp < 4; ++pp)
    for (int ci = 0; ci < 32; ++ci) {
      float wv = w1[((pp << 5) + ci) * 64 + co];
      float4 i0 = *(const float4*)&inT[sub][pp][ci][0];
      float4 i1 = *(const float4*)&inT[sub][pp][ci][4];
      acc[0] += i0.x * wv; acc[1] += i0.y * wv; acc[2] += i0.z * wv; acc[3] += i0.w * wv;
      acc[4] += i1.x * wv; acc[5] += i1.y * wv; acc[6] += i1.z * wv; acc[7] += i1.w * wv;
    }
  int smax = min(8, n - s0);
  for (int s = 0; s < smax; ++s) {
    float o = g1[co] * acc[s] * BN_INV + be1[co];
    y1[((size_t)(b * CAP1) + s0 + s) * 64 + co] = fmaxf(o, 0.f);
  }
}

// 256 threads = 4 sub-blocks x 8 sites (32 sites/block)
__global__ __launch_bounds__(256) void k_y2(
    const float* __restrict__ y1, const float* __restrict__ w2,
    const float* __restrict__ b2, const float* __restrict__ g2,
    const float* __restrict__ be2,
    const int* __restrict__ map1, const int* __restrict__ list2,
    const int* __restrict__ cnt, float* __restrict__ feats) {
  int b = blockIdx.x & 7;
  int qblk = blockIdx.x >> 3;       // 0..63
  int sub = threadIdx.x >> 6;
  int co = threadIdx.x & 63;
  int n = min(cnt[2 * BDIM + b], CAPM);
  if (qblk * 32 >= n) return;
  int s0 = qblk * 32 + sub * 8;
  __shared__ float inT[4][4][64][8];   // 32KB
  for (int idx = co; idx < 2048; idx += 64) {
    int s = idx & 7;
    int r = idx >> 3;
    int ci = r & 63, pp = r >> 6;
    float v = 0.f;
    int sg = s0 + s;
    if (sg < n) {
      int p = list2[b * CAPM + sg];
      int i = p / 125, j = p - i * 125;
      int sm = map1[(size_t)b * G1N + (2 * i + (pp >> 1)) * 250 + (2 * j + (pp & 1))];
      if (sm) v = y1[((size_t)(b * CAP1) + (sm - 1)) * 64 + ci];
    }
    inT[sub][pp][ci][s] = v;
  }
  __syncthreads();
  float acc[8];
#pragma unroll
  for (int s = 0; s < 8; ++s) acc[s] = b2[co];
#pragma unroll 2
  for (int pp = 0; pp < 4; ++pp)
    for (int ci = 0; ci < 64; ++ci) {
      float wv = w2[((pp << 6) + ci) * 64 + co];
      float4 i0 = *(const float4*)&inT[sub][pp][ci][0];
      float4 i1 = *(const float4*)&inT[sub][pp][ci][4];
      acc[0] += i0.x * wv; acc[1] += i0.y * wv; acc[2] += i0.z * wv; acc[3] += i0.w * wv;
      acc[4] += i1.x * wv; acc[5] += i1.y * wv; acc[6] += i1.z * wv; acc[7] += i1.w * wv;
    }
  int smax = min(8, n - s0);
  for (int s = 0; s < smax; ++s) {
    float o = g2[co] * acc[s] * BN_INV + be2[co];
    feats[((size_t)(b * CAPM) + s0 + s) * 64 + co] = fmaxf(o, 0.f);
  }
}

// ---------------- QKV projection (256 thr = 2 subs x 8 sites) ----------------
// Q is written PRE-SCALED by SCALE2 = ATT_SCALE*log2(e): scores arrive in the
// exp2 domain, so softmax needs no per-score multiply.

__global__ __launch_bounds__(256) void k_qkv(
    const float* __restrict__ feats, const int* __restrict__ list2,
    const int* __restrict__ cnt,
    const float* __restrict__ wpe, const float* __restrict__ bpe,
    const float* __restrict__ wq, const float* __restrict__ bq,
    const float* __restrict__ wk, const float* __restrict__ bk,
    const float* __restrict__ wv, const float* __restrict__ bv,
    int layer, _Float16* __restrict__ qf, _Float16* __restrict__ kf,
    _Float16* __restrict__ vt) {
  int b = blockIdx.x & 7;
  int qblk = blockIdx.x >> 3;       // 0..127 (16 sites each)
  int sub = threadIdx.x >> 7;
  int o = threadIdx.x & 127;
  int n = min(cnt[2 * BDIM + b], CAPM);
  if (qblk * 16 >= n) return;
  int s0 = qblk * 16 + sub * 8;
  __shared__ float hT[2][64][8];
  for (int idx = o; idx < 512; idx += 128) {
    int s = idx & 7, c = idx >> 3;
    float hv = 0.f;
    int sg = s0 + s;
    if (sg < n) {
      int p = list2[b * CAPM + sg];
      int i = p / 125, j = p - i * 125;
      hv = feats[((size_t)(b * CAPM) + sg) * 64 + c]
         + (float)i * (1.f / 125.f) * wpe[(layer * 2 + 0) * 64 + c]
         + (float)j * (1.f / 125.f) * wpe[(layer * 2 + 1) * 64 + c]
         + bpe[layer * 64 + c];
    }
    hT[sub][c][s] = hv;
  }
  __syncthreads();
  float accq[8], acck[8], accv[8];
  float bqv = bq[layer * 128 + o], bkv = bk[layer * 128 + o], bvv = bv[layer * 128 + o];
#pragma unroll
  for (int s = 0; s < 8; ++s) { accq[s] = bqv; acck[s] = bkv; accv[s] = bvv; }
  const float* wq_ = wq + (size_t)layer * 64 * 128 + o;
  const float* wk_ = wk + (size_t)layer * 64 * 128 + o;
  const float* wv_ = wv + (size_t)layer * 64 * 128 + o;
  for (int c = 0; c < 64; ++c) {
    float wqv = wq_[c * 128], wkv = wk_[c * 128], wvv = wv_[c * 128];
    float4 h0 = *(const float4*)&hT[sub][c][0];
    float4 h1 = *(const float4*)&hT[sub][c][4];
    float hh[8] = {h0.x, h0.y, h0.z, h0.w, h1.x, h1.y, h1.z, h1.w};
#pragma unroll
    for (int s = 0; s < 8; ++s) {
      accq[s] += hh[s] * wqv; acck[s] += hh[s] * wkv; accv[s] += hh[s] * wvv;
    }
  }
  int hd = o >> 5, d = o & 31;
  size_t bh = (size_t)(b * NHEADS + hd);
  int smax = min(8, n - s0);
  for (int s = 0; s < smax; ++s) {
    size_t rb = (bh * CAPM + s0 + s) * 32 + d;
    qf[rb] = (_Float16)(accq[s] * SCALE2);
    kf[rb] = (_Float16)acck[s];
    vt[(bh * 32 + d) * CAPM + s0 + s] = (_Float16)accv[s];
  }
}

// ---------------- split-K MFMA flash attention (4 waves x 2 ILP states) ------
// Block = (b, h, 16q tile); wave ks owns key-chunk ks; within a wave, TWO
// independent online-softmax states (A=even local tiles, B=odd) with private
// P buffers give two overlapping dependency chains (exact exp2-weighted merge
// at the end). Scores are in exp2 domain (Q pre-scaled). No sched fences:
// compiler-ordered LDS. PV as mfma(V,P): acc column = lane's query ->
// lane-local rescale. One __syncthreads; 4-chunk combine in LDS; f16 output.

union U4H8 { uint4 u; f16x8 h; };
union PKU  { _Float16 h[2]; unsigned int u; };

#define LOADK(K0, K1, K2, K3, T0)                                          \
  K0 = *(const f16x8*)(kf + (bh + (T0) + qr) * 32 + g8);                   \
  K1 = *(const f16x8*)(kf + (bh + (T0) + 16 + qr) * 32 + g8);              \
  K2 = *(const f16x8*)(kf + (bh + (T0) + 32 + qr) * 32 + g8);              \
  K3 = *(const f16x8*)(kf + (bh + (T0) + 48 + qr) * 32 + g8);

#define LOADV(V0, V1, V2, V3, T0)                                          \
  V0 = *(const f16x8*)(vbase + (size_t)qr * CAPM + (T0) + g8);             \
  V1 = *(const f16x8*)(vbase + (size_t)(16 + qr) * CAPM + (T0) + g8);      \
  V2 = *(const f16x8*)(vbase + (size_t)qr * CAPM + (T0) + 32 + g8);        \
  V3 = *(const f16x8*)(vbase + (size_t)(16 + qr) * CAPM + (T0) + 32 + g8);

#define PROCESS(SM, SL, A0, A1, PB, K0, K1, K2, K3, V0, V1, V2, V3, T0)    \
  {                                                                        \
    f32x4 z = {0.f, 0.f, 0.f, 0.f};                                        \
    f32x4 st0 = __builtin_amdgcn_mfma_f32_16x16x32_f16(K0, fq, z, 0, 0, 0);\
    f32x4 st1 = __builtin_amdgcn_mfma_f32_16x16x32_f16(K1, fq, z, 0, 0, 0);\
    f32x4 st2 = __builtin_amdgcn_mfma_f32_16x16x32_f16(K2, fq, z, 0, 0, 0);\
    f32x4 st3 = __builtin_amdgcn_mfma_f32_16x16x32_f16(K3, fq, z, 0, 0, 0);\
    if ((T0) + 64 > n) {                                                   \
      _Pragma("unroll") for (int r = 0; r < 4; ++r) {                      \
        if ((T0) + 4 * g + r >= n)      st0[r] = -1e30f;                   \
        if ((T0) + 16 + 4 * g + r >= n) st1[r] = -1e30f;                   \
        if ((T0) + 32 + 4 * g + r >= n) st2[r] = -1e30f;                   \
        if ((T0) + 48 + 4 * g + r >= n) st3[r] = -1e30f;                   \
      }                                                                    \
    }                                                                      \
    float tm = st0[0];                                                     \
    _Pragma("unroll") for (int r = 1; r < 4; ++r) tm = fmaxf(tm, st0[r]);  \
    _Pragma("unroll") for (int r = 0; r < 4; ++r) tm = fmaxf(tm, st1[r]);  \
    _Pragma("unroll") for (int r = 0; r < 4; ++r) tm = fmaxf(tm, st2[r]);  \
    _Pragma("unroll") for (int r = 0; r < 4; ++r) tm = fmaxf(tm, st3[r]);  \
    tm = fmaxf(tm, __shfl_xor(tm, 16));                                    \
    tm = fmaxf(tm, __shfl_xor(tm, 32));                                    \
    float mn = fmaxf(SM, tm);                                              \
    float f_ = exp2f(SM - mn);                                             \
    SM = mn;                                                               \
    float ls = 0.f;                                                        \
    {                                                                      \
      PKU a, c;                                                            \
      a.h[0] = (_Float16)exp2f(st0[0] - mn);                               \
      a.h[1] = (_Float16)exp2f(st0[1] - mn);                               \
      c.h[0] = (_Float16)exp2f(st0[2] - mn);                               \
      c.h[1] = (_Float16)exp2f(st0[3] - mn);                               \
      ls += (float)a.h[0] + (float)a.h[1] + (float)c.h[0] + (float)c.h[1]; \
      PB[(qr * 32 + 0 + 2 * g) ^ swz] = a.u;                               \
      PB[(qr * 32 + 1 + 2 * g) ^ swz] = c.u;                               \
      a.h[0] = (_Float16)exp2f(st1[0] - mn);                               \
      a.h[1] = (_Float16)exp2f(st1[1] - mn);                               \
      c.h[0] = (_Float16)exp2f(st1[2] - mn);                               \
      c.h[1] = (_Float16)exp2f(st1[3] - mn);                               \
      ls += (float)a.h[0] + (float)a.h[1] + (float)c.h[0] + (float)c.h[1]; \
      PB[(qr * 32 + 8 + 2 * g) ^ swz] = a.u;                               \
      PB[(qr * 32 + 9 + 2 * g) ^ swz] = c.u;                               \
      a.h[0] = (_Float16)exp2f(st2[0] - mn);                               \
      a.h[1] = (_Float16)exp2f(st2[1] - mn);                               \
      c.h[0] = (_Float16)exp2f(st2[2] - mn);                               \
      c.h[1] = (_Float16)exp2f(st2[3] - mn);                               \
      ls += (float)a.h[0] + (float)a.h[1] + (float)c.h[0] + (float)c.h[1]; \
      PB[(qr * 32 + 16 + 2 * g) ^ swz] = a.u;                              \
      PB[(qr * 32 + 17 + 2 * g) ^ swz] = c.u;                              \
      a.h[0] = (_Float16)exp2f(st3[0] - mn);                               \
      a.h[1] = (_Float16)exp2f(st3[1] - mn);                               \
      c.h[0] = (_Float16)exp2f(st3[2] - mn);                               \
      c.h[1] = (_Float16)exp2f(st3[3] - mn);                               \
      ls += (float)a.h[0] + (float)a.h[1] + (float)c.h[0] + (float)c.h[1]; \
      PB[(qr * 32 + 24 + 2 * g) ^ swz] = a.u;                              \
      PB[(qr * 32 + 25 + 2 * g) ^ swz] = c.u;                              \
    }                                                                      \
    SL = SL * f_ + ls;                                                     \
    U4H8 pa0, pa1;                                                         \
    pa0.u = *(const uint4*)&PB[(qr * 32 + 4 * g) ^ swz];                   \
    pa1.u = *(const uint4*)&PB[(qr * 32 + 16 + 4 * g) ^ swz];              \
    A0[0] *= f_; A0[1] *= f_; A0[2] *= f_; A0[3] *= f_;                    \
    A1[0] *= f_; A1[1] *= f_; A1[2] *= f_; A1[3] *= f_;                    \
    A0 = __builtin_amdgcn_mfma_f32_16x16x32_f16(V0, pa0.h, A0, 0, 0, 0);   \
    A1 = __builtin_amdgcn_mfma_f32_16x16x32_f16(V1, pa0.h, A1, 0, 0, 0);   \
    A0 = __builtin_amdgcn_mfma_f32_16x16x32_f16(V2, pa1.h, A0, 0, 0, 0);   \
    A1 = __builtin_amdgcn_mfma_f32_16x16x32_f16(V3, pa1.h, A1, 0, 0, 0);   \
  }

__global__ __launch_bounds__(256, 4) void k_attn(
    const _Float16* __restrict__ qf, const _Float16* __restrict__ kf,
    const _Float16* __restrict__ vt, const int* __restrict__ cnt,
    _Float16* __restrict__ obuf) {
  int b  = blockIdx.x & 7;            // image -> XCD
  int rr = blockIdx.x >> 3;
  int qt = rr & 127;
  int h  = rr >> 7;                   // 0..3
  int n = min(cnt[2 * BDIM + b], CAPM);
  int q0 = qt * 16;
  if (q0 >= n) return;               // block-uniform
  int ks = threadIdx.x >> 6;          // wave = key chunk
  int lane = threadIdx.x & 63;
  int g = lane >> 4, qr = lane & 15;
  int g8 = g * 8;
  size_t bh = (size_t)(b * NHEADS + h) * CAPM;
  const _Float16* vbase = vt + (size_t)(b * NHEADS + h) * 32 * CAPM;
  f16x8 fq = *(const f16x8*)(qf + (bh + q0 + qr) * 32 + g8);   // Q (pre-scaled)
  f32x4 aA0 = {0.f, 0.f, 0.f, 0.f}, aA1 = {0.f, 0.f, 0.f, 0.f};
  f32x4 aB0 = {0.f, 0.f, 0.f, 0.f}, aB1 = {0.f, 0.f, 0.f, 0.f};
  float mA = -1e30f, lA = 0.f, mB = -1e30f, lB = 0.f;
  __shared__ unsigned int P4[8][512];  // per-wave, per-state P tiles (16KB)
  __shared__ float partA[4][16][33];
  __shared__ float mlA[4][16][2];
  unsigned int* PA = P4[2 * ks];
  unsigned int* PB = P4[2 * ks + 1];
  int swz = (qr & 7) << 2;

  int nt = (n + 63) >> 6;
  int tpc = (nt + KSPLIT - 1) / KSPLIT;
  int tb = ks * tpc, te = min(nt, tb + tpc);
  if (tb < te) {
    f16x8 ka0, ka1, ka2, ka3, va0, va1, va2, va3;
    f16x8 kb0, kb1, kb2, kb3, vb0, vb1, vb2, vb3;
    LOADK(ka0, ka1, ka2, ka3, tb * 64)
    LOADV(va0, va1, va2, va3, tb * 64)
    for (int t = tb; t < te; t += 2) {
      if (t + 1 < te) {
        LOADK(kb0, kb1, kb2, kb3, (t + 1) * 64)
        LOADV(vb0, vb1, vb2, vb3, (t + 1) * 64)
      }
      PROCESS(mA, lA, aA0, aA1, PA, ka0, ka1, ka2, ka3, va0, va1, va2, va3, t * 64)
      if (t + 1 < te) {
        if (t + 2 < te) {
          LOADK(ka0, ka1, ka2, ka3, (t + 2) * 64)
          LOADV(va0, va1, va2, va3, (t + 2) * 64)
        }
        PROCESS(mB, lB, aB0, aB1, PB, kb0, kb1, kb2, kb3, vb0, vb1, vb2, vb3, (t + 1) * 64)
      }
    }
    // exact merge of the two states (exp2 domain)
    float mw = fmaxf(mA, mB);
    float wa = exp2f(mA - mw), wb = exp2f(mB - mw);
    lA = lA * wa + lB * wb;
#pragma unroll
    for (int r = 0; r < 4; ++r) {
      aA0[r] = aA0[r] * wa + aB0[r] * wb;
      aA1[r] = aA1[r] * wa + aB1[r] * wb;
    }
    mA = mw;
  }
  // full l per query qr (sum over 4 g-groups)
  lA += __shfl_xor(lA, 16);
  lA += __shfl_xor(lA, 32);
  // stash partials in LDS
#pragma unroll
  for (int r = 0; r < 4; ++r) {
    partA[ks][qr][4 * g + r] = aA0[r];
    partA[ks][qr][16 + 4 * g + r] = aA1[r];
  }
  if (g == 0) { mlA[ks][qr][0] = mA; mlA[ks][qr][1] = lA; }
  __syncthreads();
  // combine: thread t -> token s = t>>4, channels 2(t&15), 2(t&15)+1
  int t = threadIdx.x;
  int s = t >> 4;
  int c0 = (t & 15) * 2;
  int tok = q0 + s;
  if (tok < n) {
    float m0 = mlA[0][s][0], l0 = mlA[0][s][1];
    float m1 = mlA[1][s][0], l1 = mlA[1][s][1];
    float m2 = mlA[2][s][0], l2 = mlA[2][s][1];
    float m3 = mlA[3][s][0], l3 = mlA[3][s][1];
    float M = fmaxf(fmaxf(m0, m1), fmaxf(m2, m3));
    float w0_ = exp2f(m0 - M), w1_ = exp2f(m1 - M);
    float w2_ = exp2f(m2 - M), w3_ = exp2f(m3 - M);
    float invL = 1.f / (w0_ * l0 + w1_ * l1 + w2_ * l2 + w3_ * l3);
    float v0 = (partA[0][s][c0] * w0_ + partA[1][s][c0] * w1_ +
                partA[2][s][c0] * w2_ + partA[3][s][c0] * w3_) * invL;
    float v1 = (partA[0][s][c0 + 1] * w0_ + partA[1][s][c0 + 1] * w1_ +
                partA[2][s][c0 + 1] * w2_ + partA[3][s][c0 + 1] * w3_) * invL;
    _Float16* op = obuf + ((size_t)b * CAPM + tok) * ACH + h * DH;
    op[c0] = (_Float16)v0;
    op[c0 + 1] = (_Float16)v1;
  }
}

// ---------------- output projection + residual (4 sites, 256 thr) ------------

__global__ __launch_bounds__(256) void k_proj(
    const _Float16* __restrict__ obuf, const float* __restrict__ wo,
    const float* __restrict__ bo, const int* __restrict__ cnt,
    int layer, float* __restrict__ feats) {
  int b = blockIdx.x & 7;
  int sblk = blockIdx.x >> 3;        // 0..511
  int s0 = sblk * 4;
  int n = min(cnt[2 * BDIM + b], CAPM);
  if (s0 >= n) return;
  __shared__ float oT[128][4];
  int t = threadIdx.x;
#pragma unroll
  for (int k = 0; k < 2; ++k) {
    int id = t + k * 256;            // 512 = 128ch x 4 sites
    int c = id >> 2, s = id & 3;
    int sg = s0 + s;
    oT[c][s] = (sg < n) ? (float)obuf[((size_t)b * CAPM + sg) * ACH + c] : 0.f;
  }
  __syncthreads();
  int s = t >> 6, co = t & 63;
  float acc = bo[layer * 64 + co];
  const float* w = wo + (size_t)layer * 128 * 64 + co;
#pragma unroll 8
  for (int c = 0; c < 128; ++c) acc += oT[c][s] * w[c * 64];
  int tok = s0 + s;
  if (tok < n) feats[((size_t)(b * CAPM) + tok) * 64 + co] += acc;
}

// ---------------- pooled head (fused 2-stage reduce + GEMV) ------------------

__global__ __launch_bounds__(1024) void k_head(
    const float* __restrict__ feats, const float* __restrict__ wh,
    const float* __restrict__ bhd, const int* __restrict__ cnt,
    float* __restrict__ out) {
  int b = blockIdx.x;
  int n = min(cnt[2 * BDIM + b], CAPM);
  int c = threadIdx.x & 63, chunk = threadIdx.x >> 6;   // 16 chunks
  int lo = chunk * 128, hi = min(n, lo + 128);
  float s = 0.f;
  for (int mm = lo; mm < hi; ++mm)
    s += feats[((size_t)(b * CAPM) + mm) * 64 + c];
  __shared__ float red[16][64];
  __shared__ float pooled[64];
  red[chunk][c] = s;
  __syncthreads();
  if (threadIdx.x < 64) {
    float tot = 0.f;
#pragma unroll
    for (int k = 0; k < 16; ++k) tot += red[k][c];
    pooled[c] = tot / (float)max(n, 1);
  }
  __syncthreads();
  if (threadIdx.x < 4) {
    float o = bhd[threadIdx.x];
#pragma unroll
    for (int c2 = 0; c2 < 64; ++c2) o += pooled[c2] * wh[c2 * 4 + threadIdx.x];
    out[b * 4 + threadIdx.x] = o;
  }
}

// ---------------- launch -----------------------------------------------------

extern "C" void kernel_launch(void* const* d_in, const int* in_sizes, int n_in,
                              void* d_out, int out_size, void* d_ws, size_t ws_size,
                              hipStream_t stream) {
  const float* x   = (const float*)d_in[0];
  const float* w0  = (const float*)d_in[1];
  const float* b0  = (const float*)d_in[2];
  const float* g0  = (const float*)d_in[3];
  const float* be0 = (const float*)d_in[4];
  const float* w1  = (const float*)d_in[5];
  const float* b1  = (const float*)d_in[6];
  const float* g1  = (const float*)d_in[7];
  const float* be1 = (const float*)d_in[8];
  const float* w2  = (const float*)d_in[9];
  const float* b2  = (const float*)d_in[10];
  const float* g2  = (const float*)d_in[11];
  const float* be2 = (const float*)d_in[12];
  const float* wpe = (const float*)d_in[13];
  const float* bpe = (const float*)d_in[14];
  const float* wq  = (const float*)d_in[15];
  const float* bq  = (const float*)d_in[16];
  const float* wk  = (const float*)d_in[17];
  const float* bk  = (const float*)d_in[18];
  const float* wv  = (const float*)d_in[19];
  const float* bv  = (const float*)d_in[20];
  const float* wo  = (const float*)d_in[21];
  const float* bo  = (const float*)d_in[22];
  const float* wh  = (const float*)d_in[23];
  const float* bh  = (const float*)d_in[24];

  int* wsI = (int*)d_ws;
  float* wsF = (float*)d_ws;
  unsigned long long* bm = (unsigned long long*)(wsI + E_BM);
  _Float16* qf = (_Float16*)(wsI + E_QF);
  _Float16* kf = (_Float16*)(wsI + E_KF);
  _Float16* vt = (_Float16*)(wsI + E_VT);
  _Float16* ob = (_Float16*)(wsI + E_O);

  // Zero slot maps + counters only.
  hipMemsetAsync(d_ws, 0, E_ZEND * 4, stream);

  // level 0
  k_cnt0<<<dim3(NB0, BDIM), 256, 0, stream>>>(x, wsI + E_BC + 0 * BDIM * 1024,
                                              bm + 0 * BDIM * 4096);
  k_scan<<<BDIM, 256, 0, stream>>>(wsI + E_BC + 0 * BDIM * 1024,
                                   wsI + E_BO + 0 * BDIM * 1024,
                                   wsI + E_CNT, NB0, 0);
  k_emit0<<<dim3(NB0, BDIM), 256, 0, stream>>>(bm + 0 * BDIM * 4096,
                                               wsI + E_BO + 0 * BDIM * 1024,
                                               wsI + E_MAP0, wsI + E_LIST0);
  k_y0<<<(BDIM * CAP0 * 32) / 256, 256, 0, stream>>>(
      x, w0, b0, g0, be0, wsI + E_LIST0, wsI + E_CNT, wsF + E_Y0);
  // level 1
  k_cnt1<<<dim3(NB1, BDIM), 256, 0, stream>>>(wsI + E_MAP0,
                                              wsI + E_BC + 1 * BDIM * 1024,
                                              bm + 1 * BDIM * 4096);
  k_scan<<<BDIM, 256, 0, stream>>>(wsI + E_BC + 1 * BDIM * 1024,
                                   wsI + E_BO + 1 * BDIM * 1024,
                                   wsI + E_CNT, NB1, BDIM);
  k_emit1<<<dim3(NB1, BDIM), 256, 0, stream>>>(bm + 1 * BDIM * 4096,
                                               wsI + E_BO + 1 * BDIM * 1024,
                                               wsI + E_MAP1, wsI + E_LIST1);
  k_y1<<<BDIM * (CAP1 / 32), 256, 0, stream>>>(
      wsF + E_Y0, w1, b1, g1, be1, wsI + E_MAP0, wsI + E_LIST1, wsI + E_CNT, wsF + E_Y1);
  // level 2
  k_cnt2<<<dim3(NB2, BDIM), 256, 0, stream>>>(wsI + E_MAP1,
                                              wsI + E_BC + 2 * BDIM * 1024,
                                              bm + 2 * BDIM * 4096);
  k_scan<<<BDIM, 256, 0, stream>>>(wsI + E_BC + 2 * BDIM * 1024,
                                   wsI + E_BO + 2 * BDIM * 1024,
                                   wsI + E_CNT, NB2, 2 * BDIM);
  k_emit2<<<dim3(NB2, BDIM), 256, 0, stream>>>(bm + 2 * BDIM * 4096,
                                               wsI + E_BO + 2 * BDIM * 1024,
                                               wsI + E_LIST2);
  k_y2<<<BDIM * (CAPM / 32), 256, 0, stream>>>(
      wsF + E_Y1, w2, b2, g2, be2, wsI + E_MAP1, wsI + E_LIST2, wsI + E_CNT, wsF + E_FE);

  for (int layer = 0; layer < 2; ++layer) {
    k_qkv<<<BDIM * (CAPM / 16), 256, 0, stream>>>(
        wsF + E_FE, wsI + E_LIST2, wsI + E_CNT, wpe, bpe, wq, bq, wk, bk, wv, bv,
        layer, qf, kf, vt);
    k_attn<<<BDIM * NHEADS * (CAPM / 16), 256, 0, stream>>>(
        qf, kf, vt, wsI + E_CNT, ob);
    k_proj<<<BDIM * (CAPM / 4), 256, 0, stream>>>(
        ob, wo, bo, wsI + E_CNT, layer, wsF + E_FE);
  }

  k_head<<<BDIM, 1024, 0, stream>>>(wsF + E_FE, wh, bh, wsI + E_CNT, (float*)d_out);
}

// Round 11
// 252.242 us; speedup vs baseline: 1.2899x; 1.2899x over previous
//
#include <hip/hip_runtime.h>

// Problem constants
#define BDIM   8
#define NPIX   250000   // 500*500
#define G1N    62500    // 250*250
#define G2N    15625    // 125*125
#define NB0    977      // ceil(NPIX/256)
#define NB1    245      // ceil(G1N/256)
#define NB2    62       // ceil(G2N/256)
#define CAP0   4096
#define CAP1   4096
#define CAPM   2048
#define CH     64
#define ACH    128
#define NHEADS 4
#define DH     32
#define KSPLIT 4

static constexpr float BN_INV = 0.99999500003749969f;   // 1/sqrt(1+1e-5)
// attention scale folded into Q in exp2 domain: (1/sqrt(32)) * log2(e)
static constexpr float SCALE2 = 0.25505654734044769f;

typedef _Float16 f16x8 __attribute__((ext_vector_type(8)));
typedef float f32x4 __attribute__((ext_vector_type(4)));

// Workspace word offsets (4-byte units). Zeroed prefix: [0, E_ZEND)
static constexpr size_t E_MAP0  = 0;                                  // int [B*NPIX]
static constexpr size_t E_MAP1  = E_MAP0 + (size_t)BDIM*NPIX;         // int [B*G1N]
static constexpr size_t E_CNT   = E_MAP1 + (size_t)BDIM*G1N;          // int [32]
static constexpr size_t E_ZEND  = E_CNT + 32;
static constexpr size_t E_BC    = E_ZEND;                             // int [3][B][1024]
static constexpr size_t E_BO    = E_BC + (size_t)3*BDIM*1024;         // int [3][B][1024]
static constexpr size_t E_BM    = E_BO + (size_t)3*BDIM*1024;        // ull [3][B][1024][4]
static constexpr size_t E_LIST0 = E_BM + (size_t)3*BDIM*1024*8;      // int [B*CAP0]
static constexpr size_t E_LIST1 = E_LIST0 + (size_t)BDIM*CAP0;
static constexpr size_t E_LIST2 = E_LIST1 + (size_t)BDIM*CAP1;
static constexpr size_t E_Y0    = E_LIST2 + (size_t)BDIM*CAPM;        // f32 [B*CAP0*32]
static constexpr size_t E_Y1    = E_Y0 + (size_t)BDIM*CAP0*32;       // f32 [B*CAP1*64]
static constexpr size_t E_FE    = E_Y1 + (size_t)BDIM*CAP1*64;       // f32 [B*CAPM*64]
static constexpr size_t E_QF    = E_FE + (size_t)BDIM*CAPM*64;       // f16 [32bh][CAPM][32]
static constexpr size_t E_KF    = E_QF + (size_t)32*CAPM*32/2;
static constexpr size_t E_VT    = E_KF + (size_t)32*CAPM*32/2;       // f16 [32bh][32][CAPM]
static constexpr size_t E_O     = E_VT + (size_t)32*CAPM*32/2;       // f16 [B][CAPM][ACH]

// ---------------- deterministic compaction: count / scan / emit --------------

__device__ __forceinline__ bool act0(const float* x, int pix, int b) {
  return (pix < NPIX) && (x[(size_t)b * NPIX + pix] != 0.f);
}
__device__ __forceinline__ bool act1(const int* map0, int p, int b) {
  if (p >= G1N) return false;
  int i = p / 250, j = p - i * 250;
  const int* m = map0 + (size_t)b * NPIX + (2 * i) * 500 + 2 * j;
  return (m[0] | m[1] | m[500] | m[501]) != 0;
}
__device__ __forceinline__ bool act2(const int* map1, int p, int b) {
  if (p >= G2N) return false;
  int i = p / 125, j = p - i * 125;
  const int* m = map1 + (size_t)b * G1N + (2 * i) * 250 + 2 * j;
  return (m[0] | m[1] | m[250] | m[251]) != 0;
}

#define COUNT_BODY(ACT_EXPR)                                            \
  int idx = blockIdx.x * 256 + threadIdx.x;                             \
  int b = blockIdx.y;                                                   \
  bool act = (ACT_EXPR);                                                \
  unsigned long long mask = __ballot(act);                              \
  __shared__ int wc[4];                                                 \
  if ((threadIdx.x & 63) == 0) {                                        \
    wc[threadIdx.x >> 6] = __popcll(mask);                              \
    bm[((size_t)b * 1024 + blockIdx.x) * 4 + (threadIdx.x >> 6)] = mask;\
  }                                                                     \
  __syncthreads();                                                      \
  if (threadIdx.x == 0)                                                 \
    bcnt[b * 1024 + blockIdx.x] = wc[0] + wc[1] + wc[2] + wc[3];

__global__ void k_cnt0(const float* __restrict__ x, int* __restrict__ bcnt,
                       unsigned long long* __restrict__ bm) {
  COUNT_BODY(act0(x, idx, b))
}
__global__ void k_cnt1(const int* __restrict__ map0, int* __restrict__ bcnt,
                       unsigned long long* __restrict__ bm) {
  COUNT_BODY(act1(map0, idx, b))
}
__global__ void k_cnt2(const int* __restrict__ map1, int* __restrict__ bcnt,
                       unsigned long long* __restrict__ bm) {
  COUNT_BODY(act2(map1, idx, b))
}

// one block/image, 256 threads, shfl scan (1 barrier). nblk <= 1024.
__global__ __launch_bounds__(256) void k_scan(const int* __restrict__ bcnt,
                                              int* __restrict__ boff,
                                              int* __restrict__ cnt,
                                              int nblk, int cbase) {
  int b = blockIdx.x;
  int t = threadIdx.x;
  int base = t * 4;
  int v[4];
  int ts = 0;
#pragma unroll
  for (int u = 0; u < 4; ++u) {
    v[u] = (base + u < nblk) ? bcnt[b * 1024 + base + u] : 0;
    ts += v[u];
  }
  int lane = t & 63, w = t >> 6;
  int incl = ts;
#pragma unroll
  for (int off = 1; off < 64; off <<= 1) {
    int o = __shfl_up(incl, off, 64);
    if (lane >= off) incl += o;
  }
  __shared__ int wsum[4];
  if (lane == 63) wsum[w] = incl;
  __syncthreads();
  int woff = 0;
#pragma unroll
  for (int k = 0; k < 3; ++k) if (k < w) woff += wsum[k];
  int run = woff + incl - ts;
#pragma unroll
  for (int u = 0; u < 4; ++u) {
    if (base + u < nblk) boff[b * 1024 + base + u] = run;
    run += v[u];
  }
  if (t == 255) cnt[cbase + b] = run;
}

// emit: replay stored ballot masks (no recompute / no re-read of inputs)
#define EMIT_PROLOG                                                     \
  int idx = blockIdx.x * 256 + threadIdx.x;                             \
  int b = blockIdx.y;                                                   \
  int lane = threadIdx.x & 63;                                          \
  unsigned long long mask =                                             \
      bm[((size_t)b * 1024 + blockIdx.x) * 4 + (threadIdx.x >> 6)];     \
  bool act = (mask >> lane) & 1;                                        \
  __shared__ int wbase[4];                                              \
  if (lane == 0) wbase[threadIdx.x >> 6] = __popcll(mask);              \
  __syncthreads();                                                      \
  if (threadIdx.x == 0) {                                               \
    int s = boff[b * 1024 + blockIdx.x];                                \
    for (int w = 0; w < 4; ++w) { int c = wbase[w]; wbase[w] = s; s += c; } \
  }                                                                     \
  __syncthreads();                                                      \
  int slot = wbase[threadIdx.x >> 6] + __popcll(mask & ((1ull << lane) - 1ull));

__global__ void k_emit0(const unsigned long long* __restrict__ bm,
                        const int* __restrict__ boff,
                        int* __restrict__ map0, int* __restrict__ list0) {
  EMIT_PROLOG
  if (act && slot < CAP0) {
    list0[b * CAP0 + slot] = idx;
    map0[(size_t)b * NPIX + idx] = slot + 1;
  }
}
__global__ void k_emit1(const unsigned long long* __restrict__ bm,
                        const int* __restrict__ boff,
                        int* __restrict__ map1, int* __restrict__ list1) {
  EMIT_PROLOG
  if (act && slot < CAP1) {
    list1[b * CAP1 + slot] = idx;
    map1[(size_t)b * G1N + idx] = slot + 1;
  }
}
__global__ void k_emit2(const unsigned long long* __restrict__ bm,
                        const int* __restrict__ boff,
                        int* __restrict__ list2) {
  EMIT_PROLOG
  if (act && slot < CAPM) list2[b * CAPM + slot] = idx;
}

// ---------------- sparse convs -----------------------------------------------

__global__ void k_y0(const float* __restrict__ x, const float* __restrict__ w0,
                     const float* __restrict__ b0, const float* __restrict__ g0,
                     const float* __restrict__ be0,
                     const int* __restrict__ list0, const int* __restrict__ cnt,
                     float* __restrict__ y0) {
  int t = blockIdx.x * 256 + threadIdx.x;
  int b = t >> 17;
  int r = t & 131071;
  int slot = r >> 5, c = r & 31;
  int n = min(cnt[b], CAP0);
  if (slot >= n) return;
  int pix = list0[b * CAP0 + slot];
  int i = pix / 500, j = pix - i * 500;
  float acc = b0[c];
#pragma unroll
  for (int di = 0; di < 3; ++di) {
    int ii = i + di - 1;
    if ((unsigned)ii >= 500u) continue;
#pragma unroll
    for (int dj = 0; dj < 3; ++dj) {
      int jj = j + dj - 1;
      if ((unsigned)jj >= 500u) continue;
      acc += x[(size_t)b * NPIX + ii * 500 + jj] * w0[(di * 3 + dj) * 32 + c];
    }
  }
  float o = g0[c] * acc * BN_INV + be0[c];
  y0[((size_t)(b * CAP0) + slot) * 32 + c] = fmaxf(o, 0.f);
}

// 256 threads = 4 sub-blocks x 8 sites (32 sites/block)
__global__ __launch_bounds__(256) void k_y1(
    const float* __restrict__ y0, const float* __restrict__ w1,
    const float* __restrict__ b1, const float* __restrict__ g1,
    const float* __restrict__ be1,
    const int* __restrict__ map0, const int* __restrict__ list1,
    const int* __restrict__ cnt, float* __restrict__ y1) {
  int b = blockIdx.x & 7;
  int qblk = blockIdx.x >> 3;       // 0..127
  int sub = threadIdx.x >> 6;
  int co = threadIdx.x & 63;
  int n = min(cnt[BDIM + b], CAP1);
  if (qblk * 32 >= n) return;       // block-uniform
  int s0 = qblk * 32 + sub * 8;
  __shared__ float inT[4][4][32][8];
  for (int idx = co; idx < 1024; idx += 64) {
    int s = idx & 7;
    int r = idx >> 3;
    int ci = r & 31, pp = r >> 5;
    float v = 0.f;
    int sg = s0 + s;
    if (sg < n) {
      int p = list1[b * CAP1 + sg];
      int i = p / 250, j = p - i * 250;
      int sm = map0[(size_t)b * NPIX + (2 * i + (pp >> 1)) * 500 + (2 * j + (pp & 1))];
      if (sm) v = y0[((size_t)(b * CAP0) + (sm - 1)) * 32 + ci];
    }
    inT[sub][pp][ci][s] = v;
  }
  __syncthreads();
  float acc[8];
#pragma unroll
  for (int s = 0; s < 8; ++s) acc[s] = b1[co];
#pragma unroll 2
  for (int pp = 0; pp < 4; ++pp)
    for (int ci = 0; ci < 32; ++ci) {
      float wv = w1[((pp << 5) + ci) * 64 + co];
      float4 i0 = *(const float4*)&inT[sub][pp][ci][0];
      float4 i1 = *(const float4*)&inT[sub][pp][ci][4];
      acc[0] += i0.x * wv; acc[1] += i0.y * wv; acc[2] += i0.z * wv; acc[3] += i0.w * wv;
      acc[4] += i1.x * wv; acc[5] += i1.y * wv; acc[6] += i1.z * wv; acc[7] += i1.w * wv;
    }
  int smax = min(8, n - s0);
  for (int s = 0; s < smax; ++s) {
    float o = g1[co] * acc[s] * BN_INV + be1[co];
    y1[((size_t)(b * CAP1) + s0 + s) * 64 + co] = fmaxf(o, 0.f);
  }
}

// 256 threads = 4 sub-blocks x 8 sites (32 sites/block)
__global__ __launch_bounds__(256) void k_y2(
    const float* __restrict__ y1, const float* __restrict__ w2,
    const float* __restrict__ b2, const float* __restrict__ g2,
    const float* __restrict__ be2,
    const int* __restrict__ map1, const int* __restrict__ list2,
    const int* __restrict__ cnt, float* __restrict__ feats) {
  int b = blockIdx.x & 7;
  int qblk = blockIdx.x >> 3;       // 0..63
  int sub = threadIdx.x >> 6;
  int co = threadIdx.x & 63;
  int n = min(cnt[2 * BDIM + b], CAPM);
  if (qblk * 32 >= n) return;
  int s0 = qblk * 32 + sub * 8;
  __shared__ float inT[4][4][64][8];   // 32KB
  for (int idx = co; idx < 2048; idx += 64) {
    int s = idx & 7;
    int r = idx >> 3;
    int ci = r & 63, pp = r >> 6;
    float v = 0.f;
    int sg = s0 + s;
    if (sg < n) {
      int p = list2[b * CAPM + sg];
      int i = p / 125, j = p - i * 125;
      int sm = map1[(size_t)b * G1N + (2 * i + (pp >> 1)) * 250 + (2 * j + (pp & 1))];
      if (sm) v = y1[((size_t)(b * CAP1) + (sm - 1)) * 64 + ci];
    }
    inT[sub][pp][ci][s] = v;
  }
  __syncthreads();
  float acc[8];
#pragma unroll
  for (int s = 0; s < 8; ++s) acc[s] = b2[co];
#pragma unroll 2
  for (int pp = 0; pp < 4; ++pp)
    for (int ci = 0; ci < 64; ++ci) {
      float wv = w2[((pp << 6) + ci) * 64 + co];
      float4 i0 = *(const float4*)&inT[sub][pp][ci][0];
      float4 i1 = *(const float4*)&inT[sub][pp][ci][4];
      acc[0] += i0.x * wv; acc[1] += i0.y * wv; acc[2] += i0.z * wv; acc[3] += i0.w * wv;
      acc[4] += i1.x * wv; acc[5] += i1.y * wv; acc[6] += i1.z * wv; acc[7] += i1.w * wv;
    }
  int smax = min(8, n - s0);
  for (int s = 0; s < smax; ++s) {
    float o = g2[co] * acc[s] * BN_INV + be2[co];
    feats[((size_t)(b * CAPM) + s0 + s) * 64 + co] = fmaxf(o, 0.f);
  }
}

// ---------------- QKV projection (256 thr = 2 subs x 8 sites) ----------------
// Q is written PRE-SCALED by SCALE2 = ATT_SCALE*log2(e): scores arrive in the
// exp2 domain, so softmax needs no per-score multiply.

__global__ __launch_bounds__(256) void k_qkv(
    const float* __restrict__ feats, const int* __restrict__ list2,
    const int* __restrict__ cnt,
    const float* __restrict__ wpe, const float* __restrict__ bpe,
    const float* __restrict__ wq, const float* __restrict__ bq,
    const float* __restrict__ wk, const float* __restrict__ bk,
    const float* __restrict__ wv, const float* __restrict__ bv,
    int layer, _Float16* __restrict__ qf, _Float16* __restrict__ kf,
    _Float16* __restrict__ vt) {
  int b = blockIdx.x & 7;
  int qblk = blockIdx.x >> 3;       // 0..127 (16 sites each)
  int sub = threadIdx.x >> 7;
  int o = threadIdx.x & 127;
  int n = min(cnt[2 * BDIM + b], CAPM);
  if (qblk * 16 >= n) return;
  int s0 = qblk * 16 + sub * 8;
  __shared__ float hT[2][64][8];
  for (int idx = o; idx < 512; idx += 128) {
    int s = idx & 7, c = idx >> 3;
    float hv = 0.f;
    int sg = s0 + s;
    if (sg < n) {
      int p = list2[b * CAPM + sg];
      int i = p / 125, j = p - i * 125;
      hv = feats[((size_t)(b * CAPM) + sg) * 64 + c]
         + (float)i * (1.f / 125.f) * wpe[(layer * 2 + 0) * 64 + c]
         + (float)j * (1.f / 125.f) * wpe[(layer * 2 + 1) * 64 + c]
         + bpe[layer * 64 + c];
    }
    hT[sub][c][s] = hv;
  }
  __syncthreads();
  float accq[8], acck[8], accv[8];
  float bqv = bq[layer * 128 + o], bkv = bk[layer * 128 + o], bvv = bv[layer * 128 + o];
#pragma unroll
  for (int s = 0; s < 8; ++s) { accq[s] = bqv; acck[s] = bkv; accv[s] = bvv; }
  const float* wq_ = wq + (size_t)layer * 64 * 128 + o;
  const float* wk_ = wk + (size_t)layer * 64 * 128 + o;
  const float* wv_ = wv + (size_t)layer * 64 * 128 + o;
  for (int c = 0; c < 64; ++c) {
    float wqv = wq_[c * 128], wkv = wk_[c * 128], wvv = wv_[c * 128];
    float4 h0 = *(const float4*)&hT[sub][c][0];
    float4 h1 = *(const float4*)&hT[sub][c][4];
    float hh[8] = {h0.x, h0.y, h0.z, h0.w, h1.x, h1.y, h1.z, h1.w};
#pragma unroll
    for (int s = 0; s < 8; ++s) {
      accq[s] += hh[s] * wqv; acck[s] += hh[s] * wkv; accv[s] += hh[s] * wvv;
    }
  }
  int hd = o >> 5, d = o & 31;
  size_t bh = (size_t)(b * NHEADS + hd);
  int smax = min(8, n - s0);
  for (int s = 0; s < smax; ++s) {
    size_t rb = (bh * CAPM + s0 + s) * 32 + d;
    qf[rb] = (_Float16)(accq[s] * SCALE2);
    kf[rb] = (_Float16)acck[s];
    vt[(bh * 32 + d) * CAPM + s0 + s] = (_Float16)accv[s];
  }
}

// ---------------- split-K MFMA flash attention (4 waves = 4 K-chunks) --------
// R9 structure (single softmax state/wave — R10's 2-state spilled). exp2
// domain (Q pre-scaled); balanced max tree; EXACT defer-rescale fast path:
// when no lane's max grows, f_==1 so skip rescale entirely (deterministic).
// PV as mfma(V,P): acc column = lane's query -> lane-local rescale.

union U4H8 { uint4 u; f16x8 h; };
union PKU  { _Float16 h[2]; unsigned int u; };

#define LOADK(K0, K1, K2, K3, T0)                                          \
  K0 = *(const f16x8*)(kf + (bh + (T0) + qr) * 32 + g8);                   \
  K1 = *(const f16x8*)(kf + (bh + (T0) + 16 + qr) * 32 + g8);              \
  K2 = *(const f16x8*)(kf + (bh + (T0) + 32 + qr) * 32 + g8);              \
  K3 = *(const f16x8*)(kf + (bh + (T0) + 48 + qr) * 32 + g8);

#define LOADV(V0, V1, V2, V3, T0)                                          \
  V0 = *(const f16x8*)(vbase + (size_t)qr * CAPM + (T0) + g8);             \
  V1 = *(const f16x8*)(vbase + (size_t)(16 + qr) * CAPM + (T0) + g8);      \
  V2 = *(const f16x8*)(vbase + (size_t)qr * CAPM + (T0) + 32 + g8);        \
  V3 = *(const f16x8*)(vbase + (size_t)(16 + qr) * CAPM + (T0) + 32 + g8);

#define PROCESS(K0, K1, K2, K3, V0, V1, V2, V3, T0)                        \
  {                                                                        \
    f32x4 z = {0.f, 0.f, 0.f, 0.f};                                        \
    f32x4 st0 = __builtin_amdgcn_mfma_f32_16x16x32_f16(K0, fq, z, 0, 0, 0);\
    f32x4 st1 = __builtin_amdgcn_mfma_f32_16x16x32_f16(K1, fq, z, 0, 0, 0);\
    f32x4 st2 = __builtin_amdgcn_mfma_f32_16x16x32_f16(K2, fq, z, 0, 0, 0);\
    f32x4 st3 = __builtin_amdgcn_mfma_f32_16x16x32_f16(K3, fq, z, 0, 0, 0);\
    if ((T0) + 64 > n) {                                                   \
      _Pragma("unroll") for (int r = 0; r < 4; ++r) {                      \
        if ((T0) + 4 * g + r >= n)      st0[r] = -1e30f;                   \
        if ((T0) + 16 + 4 * g + r >= n) st1[r] = -1e30f;                   \
        if ((T0) + 32 + 4 * g + r >= n) st2[r] = -1e30f;                   \
        if ((T0) + 48 + 4 * g + r >= n) st3[r] = -1e30f;                   \
      }                                                                    \
    }                                                                      \
    float t01 = fmaxf(fmaxf(st0[0], st0[1]), fmaxf(st0[2], st0[3]));       \
    float t23 = fmaxf(fmaxf(st1[0], st1[1]), fmaxf(st1[2], st1[3]));       \
    float t45 = fmaxf(fmaxf(st2[0], st2[1]), fmaxf(st2[2], st2[3]));       \
    float t67 = fmaxf(fmaxf(st3[0], st3[1]), fmaxf(st3[2], st3[3]));       \
    float tm = fmaxf(fmaxf(t01, t23), fmaxf(t45, t67));                    \
    tm = fmaxf(tm, __shfl_xor(tm, 16));                                    \
    tm = fmaxf(tm, __shfl_xor(tm, 32));                                    \
    bool grow = tm > m;                                                    \
    float mn = grow ? tm : m;                                              \
    if (__any(grow)) {                                                     \
      float f_ = exp2f(m - mn);                                            \
      m = mn;                                                              \
      l *= f_;                                                             \
      acc0[0] *= f_; acc0[1] *= f_; acc0[2] *= f_; acc0[3] *= f_;          \
      acc1[0] *= f_; acc1[1] *= f_; acc1[2] *= f_; acc1[3] *= f_;          \
    }                                                                      \
    float ls = 0.f;                                                        \
    {                                                                      \
      PKU a, c;                                                            \
      a.h[0] = (_Float16)exp2f(st0[0] - mn);                               \
      a.h[1] = (_Float16)exp2f(st0[1] - mn);                               \
      c.h[0] = (_Float16)exp2f(st0[2] - mn);                               \
      c.h[1] = (_Float16)exp2f(st0[3] - mn);                               \
      ls += (float)a.h[0] + (float)a.h[1] + (float)c.h[0] + (float)c.h[1]; \
      P[(qr * 32 + 0 + 2 * g) ^ swz] = a.u;                                \
      P[(qr * 32 + 1 + 2 * g) ^ swz] = c.u;                                \
      a.h[0] = (_Float16)exp2f(st1[0] - mn);                               \
      a.h[1] = (_Float16)exp2f(st1[1] - mn);                               \
      c.h[0] = (_Float16)exp2f(st1[2] - mn);                               \
      c.h[1] = (_Float16)exp2f(st1[3] - mn);                               \
      ls += (float)a.h[0] + (float)a.h[1] + (float)c.h[0] + (float)c.h[1]; \
      P[(qr * 32 + 8 + 2 * g) ^ swz] = a.u;                                \
      P[(qr * 32 + 9 + 2 * g) ^ swz] = c.u;                                \
      a.h[0] = (_Float16)exp2f(st2[0] - mn);                               \
      a.h[1] = (_Float16)exp2f(st2[1] - mn);                               \
      c.h[0] = (_Float16)exp2f(st2[2] - mn);                               \
      c.h[1] = (_Float16)exp2f(st2[3] - mn);                               \
      ls += (float)a.h[0] + (float)a.h[1] + (float)c.h[0] + (float)c.h[1]; \
      P[(qr * 32 + 16 + 2 * g) ^ swz] = a.u;                               \
      P[(qr * 32 + 17 + 2 * g) ^ swz] = c.u;                               \
      a.h[0] = (_Float16)exp2f(st3[0] - mn);                               \
      a.h[1] = (_Float16)exp2f(st3[1] - mn);                               \
      c.h[0] = (_Float16)exp2f(st3[2] - mn);                               \
      c.h[1] = (_Float16)exp2f(st3[3] - mn);                               \
      ls += (float)a.h[0] + (float)a.h[1] + (float)c.h[0] + (float)c.h[1]; \
      P[(qr * 32 + 24 + 2 * g) ^ swz] = a.u;                               \
      P[(qr * 32 + 25 + 2 * g) ^ swz] = c.u;                               \
    }                                                                      \
    l += ls;                                                               \
    __builtin_amdgcn_sched_barrier(0);                                     \
    U4H8 pa0, pa1;                                                         \
    pa0.u = *(const uint4*)&P[(qr * 32 + 4 * g) ^ swz];                    \
    pa1.u = *(const uint4*)&P[(qr * 32 + 16 + 4 * g) ^ swz];               \
    acc0 = __builtin_amdgcn_mfma_f32_16x16x32_f16(V0, pa0.h, acc0, 0, 0, 0);\
    acc1 = __builtin_amdgcn_mfma_f32_16x16x32_f16(V1, pa0.h, acc1, 0, 0, 0);\
    acc0 = __builtin_amdgcn_mfma_f32_16x16x32_f16(V2, pa1.h, acc0, 0, 0, 0);\
    acc1 = __builtin_amdgcn_mfma_f32_16x16x32_f16(V3, pa1.h, acc1, 0, 0, 0);\
  }

__global__ __launch_bounds__(256) void k_attn(
    const _Float16* __restrict__ qf, const _Float16* __restrict__ kf,
    const _Float16* __restrict__ vt, const int* __restrict__ cnt,
    _Float16* __restrict__ obuf) {
  int b  = blockIdx.x & 7;            // image -> XCD
  int rr = blockIdx.x >> 3;
  int qt = rr & 127;
  int h  = rr >> 7;                   // 0..3
  int n = min(cnt[2 * BDIM + b], CAPM);
  int q0 = qt * 16;
  if (q0 >= n) return;               // block-uniform
  int ks = threadIdx.x >> 6;          // wave = key chunk
  int lane = threadIdx.x & 63;
  int g = lane >> 4, qr = lane & 15;
  int g8 = g * 8;
  size_t bh = (size_t)(b * NHEADS + h) * CAPM;
  const _Float16* vbase = vt + (size_t)(b * NHEADS + h) * 32 * CAPM;
  f16x8 fq = *(const f16x8*)(qf + (bh + q0 + qr) * 32 + g8);   // Q (pre-scaled)
  f32x4 acc0 = {0.f, 0.f, 0.f, 0.f}, acc1 = {0.f, 0.f, 0.f, 0.f};
  float m = -1e30f, l = 0.f;
  __shared__ unsigned int P4[4][512];
  __shared__ float partA[4][16][33];   // [chunk][token][ch], padded
  __shared__ float mlA[4][16][2];
  unsigned int* P = P4[ks];
  int swz = (qr & 7) << 2;

  int nt = (n + 63) >> 6;
  int tpc = (nt + KSPLIT - 1) / KSPLIT;
  int tb = ks * tpc, te = min(nt, tb + tpc);
  if (tb < te) {
    f16x8 ka0, ka1, ka2, ka3, va0, va1, va2, va3;
    f16x8 kb0, kb1, kb2, kb3, vb0, vb1, vb2, vb3;
    LOADK(ka0, ka1, ka2, ka3, tb * 64)
    LOADV(va0, va1, va2, va3, tb * 64)
    for (int t = tb; t < te; t += 2) {
      if (t + 1 < te) {
        LOADK(kb0, kb1, kb2, kb3, (t + 1) * 64)
        LOADV(vb0, vb1, vb2, vb3, (t + 1) * 64)
      }
      PROCESS(ka0, ka1, ka2, ka3, va0, va1, va2, va3, t * 64)
      if (t + 1 < te) {
        if (t + 2 < te) {
          LOADK(ka0, ka1, ka2, ka3, (t + 2) * 64)
          LOADV(va0, va1, va2, va3, (t + 2) * 64)
        }
        PROCESS(kb0, kb1, kb2, kb3, vb0, vb1, vb2, vb3, (t + 1) * 64)
      }
    }
  }
  // finalize this chunk: full l per query qr (sum over 4 g-groups)
  l += __shfl_xor(l, 16);
  l += __shfl_xor(l, 32);
  // stash partials in LDS
#pragma unroll
  for (int r = 0; r < 4; ++r) {
    partA[ks][qr][4 * g + r] = acc0[r];
    partA[ks][qr][16 + 4 * g + r] = acc1[r];
  }
  if (g == 0) { mlA[ks][qr][0] = m; mlA[ks][qr][1] = l; }
  __syncthreads();
  // combine: thread t -> token s = t>>4, channels 2(t&15), 2(t&15)+1
  int t = threadIdx.x;
  int s = t >> 4;
  int c0 = (t & 15) * 2;
  int tok = q0 + s;
  if (tok < n) {
    float m0 = mlA[0][s][0], l0 = mlA[0][s][1];
    float m1 = mlA[1][s][0], l1 = mlA[1][s][1];
    float m2 = mlA[2][s][0], l2 = mlA[2][s][1];
    float m3 = mlA[3][s][0], l3 = mlA[3][s][1];
    float M = fmaxf(fmaxf(m0, m1), fmaxf(m2, m3));
    float w0_ = exp2f(m0 - M), w1_ = exp2f(m1 - M);
    float w2_ = exp2f(m2 - M), w3_ = exp2f(m3 - M);
    float invL = 1.f / (w0_ * l0 + w1_ * l1 + w2_ * l2 + w3_ * l3);
    float v0 = (partA[0][s][c0] * w0_ + partA[1][s][c0] * w1_ +
                partA[2][s][c0] * w2_ + partA[3][s][c0] * w3_) * invL;
    float v1 = (partA[0][s][c0 + 1] * w0_ + partA[1][s][c0 + 1] * w1_ +
                partA[2][s][c0 + 1] * w2_ + partA[3][s][c0 + 1] * w3_) * invL;
    _Float16* op = obuf + ((size_t)b * CAPM + tok) * ACH + h * DH;
    op[c0] = (_Float16)v0;
    op[c0 + 1] = (_Float16)v1;
  }
}

// ---------------- output projection + residual (4 sites, 256 thr) ------------

__global__ __launch_bounds__(256) void k_proj(
    const _Float16* __restrict__ obuf, const float* __restrict__ wo,
    const float* __restrict__ bo, const int* __restrict__ cnt,
    int layer, float* __restrict__ feats) {
  int b = blockIdx.x & 7;
  int sblk = blockIdx.x >> 3;        // 0..511
  int s0 = sblk * 4;
  int n = min(cnt[2 * BDIM + b], CAPM);
  if (s0 >= n) return;
  __shared__ float oT[128][4];
  int t = threadIdx.x;
#pragma unroll
  for (int k = 0; k < 2; ++k) {
    int id = t + k * 256;            // 512 = 128ch x 4 sites
    int c = id >> 2, s = id & 3;
    int sg = s0 + s;
    oT[c][s] = (sg < n) ? (float)obuf[((size_t)b * CAPM + sg) * ACH + c] : 0.f;
  }
  __syncthreads();
  int s = t >> 6, co = t & 63;
  float acc = bo[layer * 64 + co];
  const float* w = wo + (size_t)layer * 128 * 64 + co;
#pragma unroll 8
  for (int c = 0; c < 128; ++c) acc += oT[c][s] * w[c * 64];
  int tok = s0 + s;
  if (tok < n) feats[((size_t)(b * CAPM) + tok) * 64 + co] += acc;
}

// ---------------- pooled head (fused 2-stage reduce + GEMV) ------------------

__global__ __launch_bounds__(1024) void k_head(
    const float* __restrict__ feats, const float* __restrict__ wh,
    const float* __restrict__ bhd, const int* __restrict__ cnt,
    float* __restrict__ out) {
  int b = blockIdx.x;
  int n = min(cnt[2 * BDIM + b], CAPM);
  int c = threadIdx.x & 63, chunk = threadIdx.x >> 6;   // 16 chunks
  int lo = chunk * 128, hi = min(n, lo + 128);
  float s = 0.f;
  for (int mm = lo; mm < hi; ++mm)
    s += feats[((size_t)(b * CAPM) + mm) * 64 + c];
  __shared__ float red[16][64];
  __shared__ float pooled[64];
  red[chunk][c] = s;
  __syncthreads();
  if (threadIdx.x < 64) {
    float tot = 0.f;
#pragma unroll
    for (int k = 0; k < 16; ++k) tot += red[k][c];
    pooled[c] = tot / (float)max(n, 1);
  }
  __syncthreads();
  if (threadIdx.x < 4) {
    float o = bhd[threadIdx.x];
#pragma unroll
    for (int c2 = 0; c2 < 64; ++c2) o += pooled[c2] * wh[c2 * 4 + threadIdx.x];
    out[b * 4 + threadIdx.x] = o;
  }
}

// ---------------- launch -----------------------------------------------------

extern "C" void kernel_launch(void* const* d_in, const int* in_sizes, int n_in,
                              void* d_out, int out_size, void* d_ws, size_t ws_size,
                              hipStream_t stream) {
  const float* x   = (const float*)d_in[0];
  const float* w0  = (const float*)d_in[1];
  const float* b0  = (const float*)d_in[2];
  const float* g0  = (const float*)d_in[3];
  const float* be0 = (const float*)d_in[4];
  const float* w1  = (const float*)d_in[5];
  const float* b1  = (const float*)d_in[6];
  const float* g1  = (const float*)d_in[7];
  const float* be1 = (const float*)d_in[8];
  const float* w2  = (const float*)d_in[9];
  const float* b2  = (const float*)d_in[10];
  const float* g2  = (const float*)d_in[11];
  const float* be2 = (const float*)d_in[12];
  const float* wpe = (const float*)d_in[13];
  const float* bpe = (const float*)d_in[14];
  const float* wq  = (const float*)d_in[15];
  const float* bq  = (const float*)d_in[16];
  const float* wk  = (const float*)d_in[17];
  const float* bk  = (const float*)d_in[18];
  const float* wv  = (const float*)d_in[19];
  const float* bv  = (const float*)d_in[20];
  const float* wo  = (const float*)d_in[21];
  const float* bo  = (const float*)d_in[22];
  const float* wh  = (const float*)d_in[23];
  const float* bh  = (const float*)d_in[24];

  int* wsI = (int*)d_ws;
  float* wsF = (float*)d_ws;
  unsigned long long* bm = (unsigned long long*)(wsI + E_BM);
  _Float16* qf = (_Float16*)(wsI + E_QF);
  _Float16* kf = (_Float16*)(wsI + E_KF);
  _Float16* vt = (_Float16*)(wsI + E_VT);
  _Float16* ob = (_Float16*)(wsI + E_O);

  // Zero slot maps + counters only.
  hipMemsetAsync(d_ws, 0, E_ZEND * 4, stream);

  // level 0
  k_cnt0<<<dim3(NB0, BDIM), 256, 0, stream>>>(x, wsI + E_BC + 0 * BDIM * 1024,
                                              bm + 0 * BDIM * 4096);
  k_scan<<<BDIM, 256, 0, stream>>>(wsI + E_BC + 0 * BDIM * 1024,
                                   wsI + E_BO + 0 * BDIM * 1024,
                                   wsI + E_CNT, NB0, 0);
  k_emit0<<<dim3(NB0, BDIM), 256, 0, stream>>>(bm + 0 * BDIM * 4096,
                                               wsI + E_BO + 0 * BDIM * 1024,
                                               wsI + E_MAP0, wsI + E_LIST0);
  k_y0<<<(BDIM * CAP0 * 32) / 256, 256, 0, stream>>>(
      x, w0, b0, g0, be0, wsI + E_LIST0, wsI + E_CNT, wsF + E_Y0);
  // level 1
  k_cnt1<<<dim3(NB1, BDIM), 256, 0, stream>>>(wsI + E_MAP0,
                                              wsI + E_BC + 1 * BDIM * 1024,
                                              bm + 1 * BDIM * 4096);
  k_scan<<<BDIM, 256, 0, stream>>>(wsI + E_BC + 1 * BDIM * 1024,
                                   wsI + E_BO + 1 * BDIM * 1024,
                                   wsI + E_CNT, NB1, BDIM);
  k_emit1<<<dim3(NB1, BDIM), 256, 0, stream>>>(bm + 1 * BDIM * 4096,
                                               wsI + E_BO + 1 * BDIM * 1024,
                                               wsI + E_MAP1, wsI + E_LIST1);
  k_y1<<<BDIM * (CAP1 / 32), 256, 0, stream>>>(
      wsF + E_Y0, w1, b1, g1, be1, wsI + E_MAP0, wsI + E_LIST1, wsI + E_CNT, wsF + E_Y1);
  // level 2
  k_cnt2<<<dim3(NB2, BDIM), 256, 0, stream>>>(wsI + E_MAP1,
                                              wsI + E_BC + 2 * BDIM * 1024,
                                              bm + 2 * BDIM * 4096);
  k_scan<<<BDIM, 256, 0, stream>>>(wsI + E_BC + 2 * BDIM * 1024,
                                   wsI + E_BO + 2 * BDIM * 1024,
                                   wsI + E_CNT, NB2, 2 * BDIM);
  k_emit2<<<dim3(NB2, BDIM), 256, 0, stream>>>(bm + 2 * BDIM * 4096,
                                               wsI + E_BO + 2 * BDIM * 1024,
                                               wsI + E_LIST2);
  k_y2<<<BDIM * (CAPM / 32), 256, 0, stream>>>(
      wsF + E_Y1, w2, b2, g2, be2, wsI + E_MAP1, wsI + E_LIST2, wsI + E_CNT, wsF + E_FE);

  for (int layer = 0; layer < 2; ++layer) {
    k_qkv<<<BDIM * (CAPM / 16), 256, 0, stream>>>(
        wsF + E_FE, wsI + E_LIST2, wsI + E_CNT, wpe, bpe, wq, bq, wk, bk, wv, bv,
        layer, qf, kf, vt);
    k_attn<<<BDIM * NHEADS * (CAPM / 16), 256, 0, stream>>>(
        qf, kf, vt, wsI + E_CNT, ob);
    k_proj<<<BDIM * (CAPM / 4), 256, 0, stream>>>(
        ob, wo, bo, wsI + E_CNT, layer, wsF + E_FE);
  }

  k_head<<<BDIM, 1024, 0, stream>>>(wsF + E_FE, wh, bh, wsI + E_CNT, (float*)d_out);
}

// Round 13
// 238.777 us; speedup vs baseline: 1.3626x; 1.0564x over previous
//
#include <hip/hip_runtime.h>

// Problem constants
#define BDIM   8
#define NPIX   250000   // 500*500
#define G1N    62500    // 250*250
#define G2N    15625    // 125*125
#define NB0    977      // ceil(NPIX/256)
#define NB1    245      // ceil(G1N/256)
#define NB2    62       // ceil(G2N/256)
#define NBALL  (NB0 + NB1 + NB2)
#define CAP0   4096
#define CAP1   4096
#define CAPM   2048
#define CH     64
#define ACH    128
#define NHEADS 4
#define DH     32
#define KSPLIT 4

static constexpr float BN_INV = 0.99999500003749969f;   // 1/sqrt(1+1e-5)
// attention scale folded into Q in exp2 domain: (1/sqrt(32)) * log2(e)
static constexpr float SCALE2 = 0.25505654734044769f;

typedef _Float16 f16x8 __attribute__((ext_vector_type(8)));
typedef __fp16 h16x2 __attribute__((ext_vector_type(2)));
typedef float f32x4 __attribute__((ext_vector_type(4)));

// Workspace word offsets (4-byte units). Zeroed prefix: [0, E_ZEND)
static constexpr size_t E_MAP0  = 0;                                  // int [B*NPIX]
static constexpr size_t E_MAP1  = E_MAP0 + (size_t)BDIM*NPIX;         // int [B*G1N]
static constexpr size_t E_CNT   = E_MAP1 + (size_t)BDIM*G1N;          // int [32]
static constexpr size_t E_ZEND  = E_CNT + 32;
static constexpr size_t E_BC    = E_ZEND;                             // int [3][B][1024]
static constexpr size_t E_BO    = E_BC + (size_t)3*BDIM*1024;         // (unused hole)
static constexpr size_t E_BM    = E_BO + (size_t)3*BDIM*1024;        // ull [3][B][1024][4]
static constexpr size_t E_LIST0 = E_BM + (size_t)3*BDIM*1024*8;      // int [B*CAP0]
static constexpr size_t E_LIST1 = E_LIST0 + (size_t)BDIM*CAP0;
static constexpr size_t E_LIST2 = E_LIST1 + (size_t)BDIM*CAP1;
static constexpr size_t E_Y0    = E_LIST2 + (size_t)BDIM*CAPM;        // f32 [B*CAP0*32]
static constexpr size_t E_Y1    = E_Y0 + (size_t)BDIM*CAP0*32;       // f32 [B*CAP1*64]
static constexpr size_t E_FE    = E_Y1 + (size_t)BDIM*CAP1*64;       // f32 [B*CAPM*64]
static constexpr size_t E_QF    = E_FE + (size_t)BDIM*CAPM*64;       // f16 [32bh][CAPM][32]
static constexpr size_t E_KF    = E_QF + (size_t)32*CAPM*32/2;
static constexpr size_t E_VT    = E_KF + (size_t)32*CAPM*32/2;       // f16 [32bh][32][CAPM]
static constexpr size_t E_O     = E_VT + (size_t)32*CAPM*32/2;       // f16 [B][CAPM][ACH]

// ---------------- fused deterministic compaction ----------------------------

__global__ __launch_bounds__(256) void k_cntA(const float* __restrict__ x,
                                              int* __restrict__ bcnt,
                                              unsigned long long* __restrict__ bm) {
  int bx = blockIdx.x, b = blockIdx.y, tid = threadIdx.x;
  int level, blk;
  bool act = false;
  if (bx < NB0) {
    level = 0; blk = bx;
    int idx = blk * 256 + tid;
    act = (idx < NPIX) && (x[(size_t)b * NPIX + idx] != 0.f);
  } else if (bx < NB0 + NB1) {
    level = 1; blk = bx - NB0;
    int p = blk * 256 + tid;
    if (p < G1N) {
      int i = p / 250, j = p - i * 250;
      const float* px = x + (size_t)b * NPIX + (2 * i) * 500 + 2 * j;
      act = (px[0] != 0.f) | (px[1] != 0.f) | (px[500] != 0.f) | (px[501] != 0.f);
    }
  } else {
    level = 2; blk = bx - NB0 - NB1;
    int p = blk * 256 + tid;
    if (p < G2N) {
      int i = p / 125, j = p - i * 125;
      const float* px = x + (size_t)b * NPIX + (4 * i) * 500 + 4 * j;
      bool a = false;
#pragma unroll
      for (int r = 0; r < 4; ++r)
#pragma unroll
        for (int c = 0; c < 4; ++c) a |= (px[r * 500 + c] != 0.f);
      act = a;
    }
  }
  unsigned long long mask = __ballot(act);
  size_t mbase = ((size_t)level * BDIM + b) * 1024 + blk;
  __shared__ int wc[4];
  if ((tid & 63) == 0) {
    wc[tid >> 6] = __popcll(mask);
    bm[mbase * 4 + (tid >> 6)] = mask;
  }
  __syncthreads();
  if (tid == 0) bcnt[mbase] = wc[0] + wc[1] + wc[2] + wc[3];
}

__global__ __launch_bounds__(256) void k_emitA(
    const unsigned long long* __restrict__ bm, const int* __restrict__ bcnt,
    int* __restrict__ map0, int* __restrict__ list0,
    int* __restrict__ map1, int* __restrict__ list1,
    int* __restrict__ list2, int* __restrict__ cnt) {
  int bx = blockIdx.x, b = blockIdx.y, tid = threadIdx.x;
  int level, blk, nblk, cbase;
  if (bx < NB0)            { level = 0; blk = bx;             nblk = NB0; cbase = 0; }
  else if (bx < NB0 + NB1) { level = 1; blk = bx - NB0;       nblk = NB1; cbase = BDIM; }
  else                     { level = 2; blk = bx - NB0 - NB1; nblk = NB2; cbase = 2 * BDIM; }
  size_t mbase = ((size_t)level * BDIM + b) * 1024;
  int lane = tid & 63, wv = tid >> 6;
  unsigned long long mask = bm[(mbase + blk) * 4 + wv];
  // self-prefix over preceding blocks of this (level, image)
  const int* bc = bcnt + mbase;
  int pre = 0;
  for (int k = tid; k < blk; k += 256) pre += bc[k];
#pragma unroll
  for (int off = 1; off < 64; off <<= 1) pre += __shfl_xor(pre, off);
  __shared__ int wred[4], wbase[4];
  if (lane == 0) { wred[wv] = pre; wbase[wv] = __popcll(mask); }
  __syncthreads();
  if (tid == 0) {
    int s = wred[0] + wred[1] + wred[2] + wred[3];
    for (int w = 0; w < 4; ++w) { int c = wbase[w]; wbase[w] = s; s += c; }
    if (blk == nblk - 1) cnt[cbase + b] = s;   // total for this image/level
  }
  __syncthreads();
  bool act = (mask >> lane) & 1;
  int slot = wbase[wv] + __popcll(mask & ((1ull << lane) - 1ull));
  int idx = blk * 256 + tid;
  if (level == 0) {
    if (act && slot < CAP0) {
      list0[b * CAP0 + slot] = idx;
      map0[(size_t)b * NPIX + idx] = slot + 1;
    }
  } else if (level == 1) {
    if (act && slot < CAP1) {
      list1[b * CAP1 + slot] = idx;
      map1[(size_t)b * G1N + idx] = slot + 1;
    }
  } else {
    if (act && slot < CAPM) list2[b * CAPM + slot] = idx;
  }
}

// ---------------- sparse convs -----------------------------------------------

__global__ void k_y0(const float* __restrict__ x, const float* __restrict__ w0,
                     const float* __restrict__ b0, const float* __restrict__ g0,
                     const float* __restrict__ be0,
                     const int* __restrict__ list0, const int* __restrict__ cnt,
                     float* __restrict__ y0) {
  int t = blockIdx.x * 256 + threadIdx.x;
  int b = t >> 17;
  int r = t & 131071;
  int slot = r >> 5, c = r & 31;
  int n = min(cnt[b], CAP0);
  if (slot >= n) return;
  int pix = list0[b * CAP0 + slot];
  int i = pix / 500, j = pix - i * 500;
  float acc = b0[c];
#pragma unroll
  for (int di = 0; di < 3; ++di) {
    int ii = i + di - 1;
    if ((unsigned)ii >= 500u) continue;
#pragma unroll
    for (int dj = 0; dj < 3; ++dj) {
      int jj = j + dj - 1;
      if ((unsigned)jj >= 500u) continue;
      acc += x[(size_t)b * NPIX + ii * 500 + jj] * w0[(di * 3 + dj) * 32 + c];
    }
  }
  float o = g0[c] * acc * BN_INV + be0[c];
  y0[((size_t)(b * CAP0) + slot) * 32 + c] = fmaxf(o, 0.f);
}

// 256 threads = 4 sub-blocks x 8 sites (32 sites/block)
__global__ __launch_bounds__(256) void k_y1(
    const float* __restrict__ y0, const float* __restrict__ w1,
    const float* __restrict__ b1, const float* __restrict__ g1,
    const float* __restrict__ be1,
    const int* __restrict__ map0, const int* __restrict__ list1,
    const int* __restrict__ cnt, float* __restrict__ y1) {
  int b = blockIdx.x & 7;
  int qblk = blockIdx.x >> 3;       // 0..127
  int sub = threadIdx.x >> 6;
  int co = threadIdx.x & 63;
  int n = min(cnt[BDIM + b], CAP1);
  if (qblk * 32 >= n) return;       // block-uniform
  int s0 = qblk * 32 + sub * 8;
  __shared__ float inT[4][4][32][8];
  for (int idx = co; idx < 1024; idx += 64) {
    int s = idx & 7;
    int r = idx >> 3;
    int ci = r & 31, pp = r >> 5;
    float v = 0.f;
    int sg = s0 + s;
    if (sg < n) {
      int p = list1[b * CAP1 + sg];
      int i = p / 250, j = p - i * 250;
      int sm = map0[(size_t)b * NPIX + (2 * i + (pp >> 1)) * 500 + (2 * j + (pp & 1))];
      if (sm) v = y0[((size_t)(b * CAP0) + (sm - 1)) * 32 + ci];
    }
    inT[sub][pp][ci][s] = v;
  }
  __syncthreads();
  float acc[8];
#pragma unroll
  for (int s = 0; s < 8; ++s) acc[s] = b1[co];
#pragma unroll 2
  for (int pp = 0; pp < 4; ++pp)
    for (int ci = 0; ci < 32; ++ci) {
      float wv = w1[((pp << 5) + ci) * 64 + co];
      float4 i0 = *(const float4*)&inT[sub][pp][ci][0];
      float4 i1 = *(const float4*)&inT[sub][pp][ci][4];
      acc[0] += i0.x * wv; acc[1] += i0.y * wv; acc[2] += i0.z * wv; acc[3] += i0.w * wv;
      acc[4] += i1.x * wv; acc[5] += i1.y * wv; acc[6] += i1.z * wv; acc[7] += i1.w * wv;
    }
  int smax = min(8, n - s0);
  for (int s = 0; s < smax; ++s) {
    float o = g1[co] * acc[s] * BN_INV + be1[co];
    y1[((size_t)(b * CAP1) + s0 + s) * 64 + co] = fmaxf(o, 0.f);
  }
}

// 256 threads = 4 sub-blocks x 8 sites (32 sites/block)
__global__ __launch_bounds__(256) void k_y2(
    const float* __restrict__ y1, const float* __restrict__ w2,
    const float* __restrict__ b2, const float* __restrict__ g2,
    const float* __restrict__ be2,
    const int* __restrict__ map1, const int* __restrict__ list2,
    const int* __restrict__ cnt, float* __restrict__ feats) {
  int b = blockIdx.x & 7;
  int qblk = blockIdx.x >> 3;       // 0..63
  int sub = threadIdx.x >> 6;
  int co = threadIdx.x & 63;
  int n = min(cnt[2 * BDIM + b], CAPM);
  if (qblk * 32 >= n) return;
  int s0 = qblk * 32 + sub * 8;
  __shared__ float inT[4][4][64][8];   // 32KB
  for (int idx = co; idx < 2048; idx += 64) {
    int s = idx & 7;
    int r = idx >> 3;
    int ci = r & 63, pp = r >> 6;
    float v = 0.f;
    int sg = s0 + s;
    if (sg < n) {
      int p = list2[b * CAPM + sg];
      int i = p / 125, j = p - i * 125;
      int sm = map1[(size_t)b * G1N + (2 * i + (pp >> 1)) * 250 + (2 * j + (pp & 1))];
      if (sm) v = y1[((size_t)(b * CAP1) + (sm - 1)) * 64 + ci];
    }
    inT[sub][pp][ci][s] = v;
  }
  __syncthreads();
  float acc[8];
#pragma unroll
  for (int s = 0; s < 8; ++s) acc[s] = b2[co];
#pragma unroll 2
  for (int pp = 0; pp < 4; ++pp)
    for (int ci = 0; ci < 64; ++ci) {
      float wv = w2[((pp << 6) + ci) * 64 + co];
      float4 i0 = *(const float4*)&inT[sub][pp][ci][0];
      float4 i1 = *(const float4*)&inT[sub][pp][ci][4];
      acc[0] += i0.x * wv; acc[1] += i0.y * wv; acc[2] += i0.z * wv; acc[3] += i0.w * wv;
      acc[4] += i1.x * wv; acc[5] += i1.y * wv; acc[6] += i1.z * wv; acc[7] += i1.w * wv;
    }
  int smax = min(8, n - s0);
  for (int s = 0; s < smax; ++s) {
    float o = g2[co] * acc[s] * BN_INV + be2[co];
    feats[((size_t)(b * CAPM) + s0 + s) * 64 + co] = fmaxf(o, 0.f);
  }
}

// ---------------- QKV projection (256 thr = 2 subs x 8 sites) ----------------
// Q is written PRE-SCALED by SCALE2 = ATT_SCALE*log2(e).

__global__ __launch_bounds__(256) void k_qkv(
    const float* __restrict__ feats, const int* __restrict__ list2,
    const int* __restrict__ cnt,
    const float* __restrict__ wpe, const float* __restrict__ bpe,
    const float* __restrict__ wq, const float* __restrict__ bq,
    const float* __restrict__ wk, const float* __restrict__ bk,
    const float* __restrict__ wv, const float* __restrict__ bv,
    int layer, _Float16* __restrict__ qf, _Float16* __restrict__ kf,
    _Float16* __restrict__ vt) {
  int b = blockIdx.x & 7;
  int qblk = blockIdx.x >> 3;       // 0..127 (16 sites each)
  int sub = threadIdx.x >> 7;
  int o = threadIdx.x & 127;
  int n = min(cnt[2 * BDIM + b], CAPM);
  if (qblk * 16 >= n) return;
  int s0 = qblk * 16 + sub * 8;
  __shared__ float hT[2][64][8];
  for (int idx = o; idx < 512; idx += 128) {
    int s = idx & 7, c = idx >> 3;
    float hv = 0.f;
    int sg = s0 + s;
    if (sg < n) {
      int p = list2[b * CAPM + sg];
      int i = p / 125, j = p - i * 125;
      hv = feats[((size_t)(b * CAPM) + sg) * 64 + c]
         + (float)i * (1.f / 125.f) * wpe[(layer * 2 + 0) * 64 + c]
         + (float)j * (1.f / 125.f) * wpe[(layer * 2 + 1) * 64 + c]
         + bpe[layer * 64 + c];
    }
    hT[sub][c][s] = hv;
  }
  __syncthreads();
  float accq[8], acck[8], accv[8];
  float bqv = bq[layer * 128 + o], bkv = bk[layer * 128 + o], bvv = bv[layer * 128 + o];
#pragma unroll
  for (int s = 0; s < 8; ++s) { accq[s] = bqv; acck[s] = bkv; accv[s] = bvv; }
  const float* wq_ = wq + (size_t)layer * 64 * 128 + o;
  const float* wk_ = wk + (size_t)layer * 64 * 128 + o;
  const float* wv_ = wv + (size_t)layer * 64 * 128 + o;
  for (int c = 0; c < 64; ++c) {
    float wqv = wq_[c * 128], wkv = wk_[c * 128], wvv = wv_[c * 128];
    float4 h0 = *(const float4*)&hT[sub][c][0];
    float4 h1 = *(const float4*)&hT[sub][c][4];
    float hh[8] = {h0.x, h0.y, h0.z, h0.w, h1.x, h1.y, h1.z, h1.w};
#pragma unroll
    for (int s = 0; s < 8; ++s) {
      accq[s] += hh[s] * wqv; acck[s] += hh[s] * wkv; accv[s] += hh[s] * wvv;
    }
  }
  int hd = o >> 5, d = o & 31;
  size_t bh = (size_t)(b * NHEADS + hd);
  int smax = min(8, n - s0);
  for (int s = 0; s < smax; ++s) {
    size_t rb = (bh * CAPM + s0 + s) * 32 + d;
    qf[rb] = (_Float16)(accq[s] * SCALE2);
    kf[rb] = (_Float16)acck[s];
    vt[(bh * 32 + d) * CAPM + s0 + s] = (_Float16)accv[s];
  }
}

// ---------------- split-K MFMA flash attention (4 waves = 4 K-chunks) --------
// VALU diet: QK MFMA seeded with C = -m; first-tile peel; cvt_pkrtz packs P
// pairs; fdot2 sums l from the SAME packed values; balanced max trees.

union U4H8 { uint4 u; f16x8 h; };
union PK2  { h16x2 h; unsigned int u; };

__device__ __forceinline__ void ptile(
    f16x8 K0, f16x8 K1, f16x8 K2, f16x8 K3,
    f16x8 V0, f16x8 V1, f16x8 V2, f16x8 V3,
    f16x8 fq, f32x4& acc0, f32x4& acc1, float& m, float& l, bool& first,
    unsigned int* P, int swz, int g, int qr, int n, int T0) {
  f32x4 cm = { -m, -m, -m, -m };
  f32x4 st0 = __builtin_amdgcn_mfma_f32_16x16x32_f16(K0, fq, cm, 0, 0, 0);
  f32x4 st1 = __builtin_amdgcn_mfma_f32_16x16x32_f16(K1, fq, cm, 0, 0, 0);
  f32x4 st2 = __builtin_amdgcn_mfma_f32_16x16x32_f16(K2, fq, cm, 0, 0, 0);
  f32x4 st3 = __builtin_amdgcn_mfma_f32_16x16x32_f16(K3, fq, cm, 0, 0, 0);
  if (T0 + 64 > n) {
#pragma unroll
    for (int r = 0; r < 4; ++r) {
      if (T0 + 4 * g + r >= n)      st0[r] = -1e30f;
      if (T0 + 16 + 4 * g + r >= n) st1[r] = -1e30f;
      if (T0 + 32 + 4 * g + r >= n) st2[r] = -1e30f;
      if (T0 + 48 + 4 * g + r >= n) st3[r] = -1e30f;
    }
  }
  float x0 = fmaxf(fmaxf(st0[0], st0[1]), st0[2]);
  float x1 = fmaxf(fmaxf(st0[3], st1[0]), st1[1]);
  float x2 = fmaxf(fmaxf(st1[2], st1[3]), st2[0]);
  float x3 = fmaxf(fmaxf(st2[1], st2[2]), st2[3]);
  float x4 = fmaxf(fmaxf(st3[0], st3[1]), st3[2]);
  float tm = fmaxf(fmaxf(fmaxf(x0, x1), fmaxf(x2, x3)), fmaxf(x4, st3[3]));
  tm = fmaxf(tm, __shfl_xor(tm, 16));
  tm = fmaxf(tm, __shfl_xor(tm, 32));
  bool gw = first || (__any(tm > 0.f) != 0);
  float d = 0.f;
  if (gw) {
    d = first ? tm : fmaxf(tm, 0.f);
    if (!first) {
      float f_ = exp2f(-d);
      l *= f_;
      acc0 *= f_;
      acc1 *= f_;
    }
    m += d;
    first = false;
  }
  PK2 a0, a1, a2, a3, a4, a5, a6, a7;
  a0.h = __builtin_amdgcn_cvt_pkrtz(exp2f(st0[0] - d), exp2f(st0[1] - d));
  a1.h = __builtin_amdgcn_cvt_pkrtz(exp2f(st0[2] - d), exp2f(st0[3] - d));
  a2.h = __builtin_amdgcn_cvt_pkrtz(exp2f(st1[0] - d), exp2f(st1[1] - d));
  a3.h = __builtin_amdgcn_cvt_pkrtz(exp2f(st1[2] - d), exp2f(st1[3] - d));
  a4.h = __builtin_amdgcn_cvt_pkrtz(exp2f(st2[0] - d), exp2f(st2[1] - d));
  a5.h = __builtin_amdgcn_cvt_pkrtz(exp2f(st2[2] - d), exp2f(st2[3] - d));
  a6.h = __builtin_amdgcn_cvt_pkrtz(exp2f(st3[0] - d), exp2f(st3[1] - d));
  a7.h = __builtin_amdgcn_cvt_pkrtz(exp2f(st3[2] - d), exp2f(st3[3] - d));
  h16x2 one2 = { (__fp16)1.f, (__fp16)1.f };
  float ls = 0.f;
  ls = __builtin_amdgcn_fdot2(a0.h, one2, ls, false);
  ls = __builtin_amdgcn_fdot2(a1.h, one2, ls, false);
  ls = __builtin_amdgcn_fdot2(a2.h, one2, ls, false);
  ls = __builtin_amdgcn_fdot2(a3.h, one2, ls, false);
  ls = __builtin_amdgcn_fdot2(a4.h, one2, ls, false);
  ls = __builtin_amdgcn_fdot2(a5.h, one2, ls, false);
  ls = __builtin_amdgcn_fdot2(a6.h, one2, ls, false);
  ls = __builtin_amdgcn_fdot2(a7.h, one2, ls, false);
  l += ls;
  P[(qr * 32 + 0 + 2 * g) ^ swz] = a0.u;
  P[(qr * 32 + 1 + 2 * g) ^ swz] = a1.u;
  P[(qr * 32 + 8 + 2 * g) ^ swz] = a2.u;
  P[(qr * 32 + 9 + 2 * g) ^ swz] = a3.u;
  P[(qr * 32 + 16 + 2 * g) ^ swz] = a4.u;
  P[(qr * 32 + 17 + 2 * g) ^ swz] = a5.u;
  P[(qr * 32 + 24 + 2 * g) ^ swz] = a6.u;
  P[(qr * 32 + 25 + 2 * g) ^ swz] = a7.u;
  __builtin_amdgcn_sched_barrier(0);
  U4H8 pa0, pa1;
  pa0.u = *(const uint4*)&P[(qr * 32 + 4 * g) ^ swz];
  pa1.u = *(const uint4*)&P[(qr * 32 + 16 + 4 * g) ^ swz];
  acc0 = __builtin_amdgcn_mfma_f32_16x16x32_f16(V0, pa0.h, acc0, 0, 0, 0);
  acc1 = __builtin_amdgcn_mfma_f32_16x16x32_f16(V1, pa0.h, acc1, 0, 0, 0);
  acc0 = __builtin_amdgcn_mfma_f32_16x16x32_f16(V2, pa1.h, acc0, 0, 0, 0);
  acc1 = __builtin_amdgcn_mfma_f32_16x16x32_f16(V3, pa1.h, acc1, 0, 0, 0);
}

#define LOADK(K0, K1, K2, K3, T0)                                          \
  K0 = *(const f16x8*)(kf + (bh + (T0) + qr) * 32 + g8);                   \
  K1 = *(const f16x8*)(kf + (bh + (T0) + 16 + qr) * 32 + g8);              \
  K2 = *(const f16x8*)(kf + (bh + (T0) + 32 + qr) * 32 + g8);              \
  K3 = *(const f16x8*)(kf + (bh + (T0) + 48 + qr) * 32 + g8);

#define LOADV(V0, V1, V2, V3, T0)                                          \
  V0 = *(const f16x8*)(vbase + (size_t)qr * CAPM + (T0) + g8);             \
  V1 = *(const f16x8*)(vbase + (size_t)(16 + qr) * CAPM + (T0) + g8);      \
  V2 = *(const f16x8*)(vbase + (size_t)qr * CAPM + (T0) + 32 + g8);        \
  V3 = *(const f16x8*)(vbase + (size_t)(16 + qr) * CAPM + (T0) + 32 + g8);

__global__ __launch_bounds__(256) void k_attn(
    const _Float16* __restrict__ qf, const _Float16* __restrict__ kf,
    const _Float16* __restrict__ vt, const int* __restrict__ cnt,
    _Float16* __restrict__ obuf) {
  int b  = blockIdx.x & 7;            // image -> XCD
  int rr = blockIdx.x >> 3;
  int qt = rr & 127;
  int h  = rr >> 7;                   // 0..3
  int n = min(cnt[2 * BDIM + b], CAPM);
  int q0 = qt * 16;
  if (q0 >= n) return;               // block-uniform
  int ks = threadIdx.x >> 6;          // wave = key chunk
  int lane = threadIdx.x & 63;
  int g = lane >> 4, qr = lane & 15;
  int g8 = g * 8;
  size_t bh = (size_t)(b * NHEADS + h) * CAPM;
  const _Float16* vbase = vt + (size_t)(b * NHEADS + h) * 32 * CAPM;
  f16x8 fq = *(const f16x8*)(qf + (bh + q0 + qr) * 32 + g8);   // Q (pre-scaled)
  f32x4 acc0 = {0.f, 0.f, 0.f, 0.f}, acc1 = {0.f, 0.f, 0.f, 0.f};
  float m = 0.f, l = 0.f;             // m=0 + first-flag (see ptile)
  bool first = true;
  __shared__ unsigned int P4[4][512];
  __shared__ float partA[4][16][33];   // [chunk][token][ch], padded
  __shared__ float mlA[4][16][2];
  unsigned int* P = P4[ks];
  int swz = (qr & 7) << 2;

  int nt = (n + 63) >> 6;
  int tpc = (nt + KSPLIT - 1) / KSPLIT;
  int tb = ks * tpc, te = min(nt, tb + tpc);
  if (tb < te) {
    f16x8 ka0, ka1, ka2, ka3, va0, va1, va2, va3;
    f16x8 kb0, kb1, kb2, kb3, vb0, vb1, vb2, vb3;
    LOADK(ka0, ka1, ka2, ka3, tb * 64)
    LOADV(va0, va1, va2, va3, tb * 64)
    for (int t = tb; t < te; t += 2) {
      if (t + 1 < te) {
        LOADK(kb0, kb1, kb2, kb3, (t + 1) * 64)
        LOADV(vb0, vb1, vb2, vb3, (t + 1) * 64)
      }
      ptile(ka0, ka1, ka2, ka3, va0, va1, va2, va3, fq, acc0, acc1, m, l,
            first, P, swz, g, qr, n, t * 64);
      if (t + 1 < te) {
        if (t + 2 < te) {
          LOADK(ka0, ka1, ka2, ka3, (t + 2) * 64)
          LOADV(va0, va1, va2, va3, (t + 2) * 64)
        }
        ptile(kb0, kb1, kb2, kb3, vb0, vb1, vb2, vb3, fq, acc0, acc1, m, l,
              first, P, swz, g, qr, n, (t + 1) * 64);
      }
    }
  }
  // finalize this chunk: full l per query qr (sum over 4 g-groups)
  l += __shfl_xor(l, 16);
  l += __shfl_xor(l, 32);
  // stash partials in LDS (empty chunk: m=0,l=0,acc=0 -> handled in combine
  // since w*l contribution is 0 and acc is 0)
#pragma unroll
  for (int r = 0; r < 4; ++r) {
    partA[ks][qr][4 * g + r] = acc0[r];
    partA[ks][qr][16 + 4 * g + r] = acc1[r];
  }
  if (g == 0) { mlA[ks][qr][0] = first ? -1e30f : m; mlA[ks][qr][1] = l; }
  __syncthreads();
  // combine: thread t -> token s = t>>4, channels 2(t&15), 2(t&15)+1
  int t = threadIdx.x;
  int s = t >> 4;
  int c0 = (t & 15) * 2;
  int tok = q0 + s;
  if (tok < n) {
    float m0 = mlA[0][s][0], l0 = mlA[0][s][1];
    float m1 = mlA[1][s][0], l1 = mlA[1][s][1];
    float m2 = mlA[2][s][0], l2 = mlA[2][s][1];
    float m3 = mlA[3][s][0], l3 = mlA[3][s][1];
    float M = fmaxf(fmaxf(m0, m1), fmaxf(m2, m3));
    float w0_ = exp2f(m0 - M), w1_ = exp2f(m1 - M);
    float w2_ = exp2f(m2 - M), w3_ = exp2f(m3 - M);
    float invL = 1.f / (w0_ * l0 + w1_ * l1 + w2_ * l2 + w3_ * l3);
    float v0 = (partA[0][s][c0] * w0_ + partA[1][s][c0] * w1_ +
                partA[2][s][c0] * w2_ + partA[3][s][c0] * w3_) * invL;
    float v1 = (partA[0][s][c0 + 1] * w0_ + partA[1][s][c0 + 1] * w1_ +
                partA[2][s][c0 + 1] * w2_ + partA[3][s][c0 + 1] * w3_) * invL;
    _Float16* op = obuf + ((size_t)b * CAPM + tok) * ACH + h * DH;
    op[c0] = (_Float16)v0;
    op[c0 + 1] = (_Float16)v1;
  }
}

// ---------------- output projection + residual (4 sites, 256 thr) ------------

__global__ __launch_bounds__(256) void k_proj(
    const _Float16* __restrict__ obuf, const float* __restrict__ wo,
    const float* __restrict__ bo, const int* __restrict__ cnt,
    int layer, float* __restrict__ feats) {
  int b = blockIdx.x & 7;
  int sblk = blockIdx.x >> 3;        // 0..511
  int s0 = sblk * 4;
  int n = min(cnt[2 * BDIM + b], CAPM);
  if (s0 >= n) return;
  __shared__ float oT[128][4];
  int t = threadIdx.x;
#pragma unroll
  for (int k = 0; k < 2; ++k) {
    int id = t + k * 256;            // 512 = 128ch x 4 sites
    int c = id >> 2, s = id & 3;
    int sg = s0 + s;
    oT[c][s] = (sg < n) ? (float)obuf[((size_t)b * CAPM + sg) * ACH + c] : 0.f;
  }
  __syncthreads();
  int s = t >> 6, co = t & 63;
  float acc = bo[layer * 64 + co];
  const float* w = wo + (size_t)layer * 128 * 64 + co;
#pragma unroll 8
  for (int c = 0; c < 128; ++c) acc += oT[c][s] * w[c * 64];
  int tok = s0 + s;
  if (tok < n) feats[((size_t)(b * CAPM) + tok) * 64 + co] += acc;
}

// ---------------- pooled head (fused 2-stage reduce + GEMV) ------------------

__global__ __launch_bounds__(1024) void k_head(
    const float* __restrict__ feats, const float* __restrict__ wh,
    const float* __restrict__ bhd, const int* __restrict__ cnt,
    float* __restrict__ out) {
  int b = blockIdx.x;
  int n = min(cnt[2 * BDIM + b], CAPM);
  int c = threadIdx.x & 63, chunk = threadIdx.x >> 6;   // 16 chunks
  int lo = chunk * 128, hi = min(n, lo + 128);
  float s = 0.f;
  for (int mm = lo; mm < hi; ++mm)
    s += feats[((size_t)(b * CAPM) + mm) * 64 + c];
  __shared__ float red[16][64];
  __shared__ float pooled[64];
  red[chunk][c] = s;
  __syncthreads();
  if (threadIdx.x < 64) {
    float tot = 0.f;
#pragma unroll
    for (int k = 0; k < 16; ++k) tot += red[k][c];
    pooled[c] = tot / (float)max(n, 1);
  }
  __syncthreads();
  if (threadIdx.x < 4) {
    float o = bhd[threadIdx.x];
#pragma unroll
    for (int c2 = 0; c2 < 64; ++c2) o += pooled[c2] * wh[c2 * 4 + threadIdx.x];
    out[b * 4 + threadIdx.x] = o;
  }
}

// ---------------- launch -----------------------------------------------------

extern "C" void kernel_launch(void* const* d_in, const int* in_sizes, int n_in,
                              void* d_out, int out_size, void* d_ws, size_t ws_size,
                              hipStream_t stream) {
  const float* x   = (const float*)d_in[0];
  const float* w0  = (const float*)d_in[1];
  const float* b0  = (const float*)d_in[2];
  const float* g0  = (const float*)d_in[3];
  const float* be0 = (const float*)d_in[4];
  const float* w1  = (const float*)d_in[5];
  const float* b1  = (const float*)d_in[6];
  const float* g1  = (const float*)d_in[7];
  const float* be1 = (const float*)d_in[8];
  const float* w2  = (const float*)d_in[9];
  const float* b2  = (const float*)d_in[10];
  const float* g2  = (const float*)d_in[11];
  const float* be2 = (const float*)d_in[12];
  const float* wpe = (const float*)d_in[13];
  const float* bpe = (const float*)d_in[14];
  const float* wq  = (const float*)d_in[15];
  const float* bq  = (const float*)d_in[16];
  const float* wk  = (const float*)d_in[17];
  const float* bk  = (const float*)d_in[18];
  const float* wv  = (const float*)d_in[19];
  const float* bv  = (const float*)d_in[20];
  const float* wo  = (const float*)d_in[21];
  const float* bo  = (const float*)d_in[22];
  const float* wh  = (const float*)d_in[23];
  const float* bh  = (const float*)d_in[24];

  int* wsI = (int*)d_ws;
  float* wsF = (float*)d_ws;
  unsigned long long* bm = (unsigned long long*)(wsI + E_BM);
  _Float16* qf = (_Float16*)(wsI + E_QF);
  _Float16* kf = (_Float16*)(wsI + E_KF);
  _Float16* vt = (_Float16*)(wsI + E_VT);
  _Float16* ob = (_Float16*)(wsI + E_O);

  // Zero slot maps + counters only.
  hipMemsetAsync(d_ws, 0, E_ZEND * 4, stream);

  k_cntA<<<dim3(NBALL, BDIM), 256, 0, stream>>>(x, wsI + E_BC, bm);
  k_emitA<<<dim3(NBALL, BDIM), 256, 0, stream>>>(
      bm, wsI + E_BC, wsI + E_MAP0, wsI + E_LIST0, wsI + E_MAP1, wsI + E_LIST1,
      wsI + E_LIST2, wsI + E_CNT);

  k_y0<<<(BDIM * CAP0 * 32) / 256, 256, 0, stream>>>(
      x, w0, b0, g0, be0, wsI + E_LIST0, wsI + E_CNT, wsF + E_Y0);
  k_y1<<<BDIM * (CAP1 / 32), 256, 0, stream>>>(
      wsF + E_Y0, w1, b1, g1, be1, wsI + E_MAP0, wsI + E_LIST1, wsI + E_CNT, wsF + E_Y1);
  k_y2<<<BDIM * (CAPM / 32), 256, 0, stream>>>(
      wsF + E_Y1, w2, b2, g2, be2, wsI + E_MAP1, wsI + E_LIST2, wsI + E_CNT, wsF + E_FE);

  for (int layer = 0; layer < 2; ++layer) {
    k_qkv<<<BDIM * (CAPM / 16), 256, 0, stream>>>(
        wsF + E_FE, wsI + E_LIST2, wsI + E_CNT, wpe, bpe, wq, bq, wk, bk, wv, bv,
        layer, qf, kf, vt);
    k_attn<<<BDIM * NHEADS * (CAPM / 16), 256, 0, stream>>>(
        qf, kf, vt, wsI + E_CNT, ob);
    k_proj<<<BDIM * (CAPM / 4), 256, 0, stream>>>(
        ob, wo, bo, wsI + E_CNT, layer, wsF + E_FE);
  }

  k_head<<<BDIM, 1024, 0, stream>>>(wsF + E_FE, wh, bh, wsI + E_CNT, (float*)d_out);
}